// Round 2
// baseline (19693.787 us; speedup 1.0000x reference)
//
#include <hip/hip_runtime.h>
#include <stdint.h>
#include <math.h>

// ---------------------------------------------------------------------------
// Fused single-kernel graph-generator RNN (B=512, H=256, 50 steps, window 12).
// 256 WGs x 256 thr persistent kernel; hand-rolled device-scope grid barrier
// (all WGs provably co-resident: 22KB LDS, 4 waves -> >=7 WGs/CU capacity).
// Per-thread GEMM / classifier arithmetic is VERBATIM from the passing
// round-1 kernels => bit-identical outputs; only scheduling changed.
// ---------------------------------------------------------------------------

#define HDIM 256
#define NWG 256
#define NTHR 256

// workspace layout (floats)
#define WS_EMB   0u            // 2 * 131072 (ring of node_embs)
#define WS_EGI   262144u       // 13 * 393216 (edge input-gate ring)
#define WS_NGI   5373952u      // 393216 (node input gates)
#define WS_H0    5767168u      // 131072 (latent projection)
#define WS_EHF   5898240u      // 2 * 131072 (edge_h final ping-pong)
#define WS_EOUT  6160384u      // 12 * 131072 (edge scan outputs)
#define WS_NN    7733248u      // 512 (num_nodes)
#define WS_CNT   7733760u      // 1 uint32 barrier counter

// output layout (floats)
#define O_NF 512u              // node feats [512][50][51]
#define O_EF 1306112u          // edge feats [522][512][9]
#define O_NL 3711488u          // node logprobs [512][50][3]
#define O_EL 3788288u          // edge logprobs [522][512][2]

// ---------------- threefry2x32 (exact JAX semantics) ----------------
__host__ __device__ inline void tf2x32(uint32_t k0, uint32_t k1,
                                       uint32_t x0, uint32_t x1,
                                       uint32_t& o0, uint32_t& o1) {
  uint32_t ks2 = k0 ^ k1 ^ 0x1BD11BDAu;
#define TFR(r) { x0 += x1; x1 = (x1 << r) | (x1 >> (32 - r)); x1 ^= x0; }
  x0 += k0; x1 += k1;
  TFR(13) TFR(15) TFR(26) TFR(6)
  x0 += k1; x1 += ks2 + 1u;
  TFR(17) TFR(29) TFR(16) TFR(24)
  x0 += ks2; x1 += k0 + 2u;
  TFR(13) TFR(15) TFR(26) TFR(6)
  x0 += k0; x1 += k1 + 3u;
  TFR(17) TFR(29) TFR(16) TFR(24)
  x0 += k1; x1 += ks2 + 4u;
  TFR(13) TFR(15) TFR(26) TFR(6)
  x0 += ks2; x1 += k0 + 5u;
#undef TFR
  o0 = x0; o1 = x1;
}

__device__ inline float gumbel_at(uint32_t k0, uint32_t k1, uint32_t idx) {
  uint32_t o0, o1;
  tf2x32(k0, k1, 0u, idx, o0, o1);
  uint32_t bits = o0 ^ o1;
  float u = __uint_as_float((bits >> 9) | 0x3f800000u) - 1.0f;
  u = fmaxf(u, 1.1754943508222875e-38f);
  return -logf(-logf(u));
}

// ---------------- grid barrier (device-scope, spin) ----------------
__device__ __forceinline__ void gsync(uint32_t* cnt, uint32_t& tgt) {
  __syncthreads();
  tgt += NWG;
  if (threadIdx.x == 0) {
    __threadfence();                         // release
    atomicAdd(cnt, 1u);                      // device-scope by default
    while (__hip_atomic_load(cnt, __ATOMIC_RELAXED,
                             __HIP_MEMORY_SCOPE_AGENT) < tgt)
      __builtin_amdgcn_s_sleep(2);
    __threadfence();                         // acquire
  }
  __syncthreads();
}

// ---------------- fused GRU GEMM tile (verbatim round-1 math) ----------------
// gi==nullptr: out[512][768] = A@W.T + bias
// gi!=nullptr: gh = (A+A2)@W.T + bias; GRU-combine with gi; h=(A+A2)
__device__ __noinline__ void gemm_tile(const float* __restrict__ A,
                                       const float* __restrict__ A2,
                                       const float* __restrict__ W,
                                       const float* __restrict__ bias,
                                       const float* __restrict__ gi,
                                       float* __restrict__ out,
                                       float* __restrict__ out2,
                                       float (*As)[68], float (*Ws)[68]) {
  const int t  = threadIdx.x;
  const int m0 = (blockIdx.x & 15) * 32;
  const int j0 = (blockIdx.x >> 4) * 16;
  const int jj = t & 15;
  const int mr = (t >> 4) * 2;
  float a00 = 0.f, a01 = 0.f, a02 = 0.f, a10 = 0.f, a11 = 0.f, a12 = 0.f;
  for (int k0 = 0; k0 < HDIM; k0 += 64) {
#pragma unroll
    for (int r = 0; r < 2; ++r) {            // stage A (32x64)
      int idx = t + r * 256;
      int row = idx >> 4;
      int c = (idx & 15) << 2;
      float4 v = *(const float4*)(A + (size_t)(m0 + row) * HDIM + k0 + c);
      if (A2) {
        float4 v2 = *(const float4*)(A2 + (size_t)(m0 + row) * HDIM + k0 + c);
        v.x += v2.x; v.y += v2.y; v.z += v2.z; v.w += v2.w;
      }
      *(float4*)&As[row][c] = v;
    }
#pragma unroll
    for (int r = 0; r < 3; ++r) {            // stage W (48x64)
      int idx = t + r * 256;
      int row = idx >> 4;
      int c = (idx & 15) << 2;
      int g = row >> 4, jl = row & 15;
      *(float4*)&Ws[row][c] =
          *(const float4*)(W + (size_t)(g * 256 + j0 + jl) * HDIM + k0 + c);
    }
    __syncthreads();
#pragma unroll
    for (int kk = 0; kk < 64; kk += 4) {
      float4 x0 = *(const float4*)&As[mr][kk];
      float4 x1 = *(const float4*)&As[mr + 1][kk];
      float4 w0 = *(const float4*)&Ws[jj][kk];
      float4 w1 = *(const float4*)&Ws[16 + jj][kk];
      float4 w2 = *(const float4*)&Ws[32 + jj][kk];
      a00 += x0.x * w0.x + x0.y * w0.y + x0.z * w0.z + x0.w * w0.w;
      a01 += x0.x * w1.x + x0.y * w1.y + x0.z * w1.z + x0.w * w1.w;
      a02 += x0.x * w2.x + x0.y * w2.y + x0.z * w2.z + x0.w * w2.w;
      a10 += x1.x * w0.x + x1.y * w0.y + x1.z * w0.z + x1.w * w0.w;
      a11 += x1.x * w1.x + x1.y * w1.y + x1.z * w1.z + x1.w * w1.w;
      a12 += x1.x * w2.x + x1.y * w2.y + x1.z * w2.z + x1.w * w2.w;
    }
    __syncthreads();
  }
  const int col = j0 + jj;
#pragma unroll
  for (int ml = 0; ml < 2; ++ml) {
    int m = m0 + mr + ml;
    float g0 = ml ? a10 : a00;
    float g1 = ml ? a11 : a01;
    float g2 = ml ? a12 : a02;
    if (!gi) {
      out[(size_t)m * 768 + col]       = g0 + bias[col];
      out[(size_t)m * 768 + 256 + col] = g1 + bias[256 + col];
      out[(size_t)m * 768 + 512 + col] = g2 + bias[512 + col];
    } else {
      float hr = g0 + bias[col];
      float hz = g1 + bias[256 + col];
      float hn = g2 + bias[512 + col];
      float ir  = gi[(size_t)m * 768 + col];
      float iz  = gi[(size_t)m * 768 + 256 + col];
      float inn = gi[(size_t)m * 768 + 512 + col];
      float h = A[(size_t)m * HDIM + col] + (A2 ? A2[(size_t)m * HDIM + col] : 0.f);
      float r  = 1.f / (1.f + expf(-(ir + hr)));
      float zg = 1.f / (1.f + expf(-(iz + hz)));
      float n  = tanhf(inn + r * hn);
      float hv = (1.f - zg) * n + zg * h;
      out[(size_t)m * HDIM + col] = hv;
      if (out2) out2[(size_t)m * HDIM + col] = hv;
    }
  }
}

// ---------------- node classifiers (verbatim row math) ----------------
__device__ __noinline__ void node_cls_all(
    const float* __restrict__ emb, const float* __restrict__ W0,
    const float* __restrict__ b0, const float* __restrict__ W1,
    const float* __restrict__ b1, const float* __restrict__ W2,
    const float* __restrict__ b2, float* __restrict__ out_feats,
    float* __restrict__ out_lp, float* __restrict__ num_nodes, int step) {
  const int gw = blockIdx.x * 4 + (threadIdx.x >> 6);
  if (gw & 1) return;
  const int b = gw >> 1;
  if (b >= 512) return;
  const int lane = threadIdx.x & 63;
  uint32_t ka0, ka1, kb0, kb1, kc0, kc1;
  tf2x32(0u, 42u, 0u, (uint32_t)(step * 100 + 0), ka0, ka1);
  tf2x32(0u, 42u, 0u, (uint32_t)(step * 100 + 1), kb0, kb1);
  tf2x32(0u, 42u, 0u, (uint32_t)(step * 100 + 2), kc0, kc1);

  const float e0 = emb[(size_t)b * HDIM + lane];
  const float e1 = emb[(size_t)b * HDIM + lane + 64];
  const float e2 = emb[(size_t)b * HDIM + lane + 128];
  const float e3 = emb[(size_t)b * HDIM + lane + 192];

  auto phase = [&](const float* W, const float* bb, int nf, uint32_t kk0,
                   uint32_t kk1, int coff, int jidx, bool do_arg) {
    float ml = 0.f;
    for (int jf = 0; jf < nf; ++jf) {
      const float* wr = W + (size_t)jf * HDIM;
      float p = e0 * wr[lane] + e1 * wr[lane + 64] + e2 * wr[lane + 128] +
                e3 * wr[lane + 192];
#pragma unroll
      for (int d = 32; d; d >>= 1) p += __shfl_xor(p, d);
      if (lane == jf) ml = p + bb[jf];
    }
    const bool act = lane < nf;
    float g = act ? gumbel_at(kk0, kk1, (uint32_t)(b * nf + lane)) : 0.f;
    float tv = act ? (ml + g) / 1e-3f : -INFINITY;
    float mx = tv;
#pragma unroll
    for (int d = 32; d; d >>= 1) mx = fmaxf(mx, __shfl_xor(mx, d));
    float e = act ? expf(tv - mx) : 0.f;
    float se = e;
#pragma unroll
    for (int d = 32; d; d >>= 1) se += __shfl_xor(se, d);
    float s = act ? e / se : 0.f;
    float mx2 = act ? ml : -INFINITY;
#pragma unroll
    for (int d = 32; d; d >>= 1) mx2 = fmaxf(mx2, __shfl_xor(mx2, d));
    float e2v = act ? expf(ml - mx2) : 0.f;
    float se2 = e2v;
#pragma unroll
    for (int d = 32; d; d >>= 1) se2 += __shfl_xor(se2, d);
    float logp = ml - mx2 - logf(se2);
    float w = act ? s * logp : 0.f;
#pragma unroll
    for (int d = 32; d; d >>= 1) w += __shfl_xor(w, d);
    if (act) out_feats[((size_t)b * 50 + step) * 51 + coff + lane] = s;
    if (lane == 0) out_lp[((size_t)b * 50 + step) * 3 + jidx] = w;
    if (do_arg) {
      float av = act ? s : -1.f;
      int ai = lane;
#pragma unroll
      for (int d = 32; d; d >>= 1) {
        float ov = __shfl_xor(av, d);
        int oi = __shfl_xor(ai, d);
        if (ov > av || (ov == av && oi < ai)) { av = ov; ai = oi; }
      }
      if (lane == 0 && ai == 39 && num_nodes[b] == -1.0f)
        num_nodes[b] = (float)(step + 1);
    }
  };
  phase(W0, b0, 40, ka0, ka1, 0, 0, true);
  phase(W1, b1, 6, kb0, kb1, 40, 1, false);
  phase(W2, b2, 5, kc0, kc1, 46, 2, false);
}

// ---------------- edge classifiers (verbatim row math) ----------------
__device__ __noinline__ void edge_cls_all(
    const float* __restrict__ eout, const float* __restrict__ W0,
    const float* __restrict__ b0, const float* __restrict__ W1,
    const float* __restrict__ b1, float* __restrict__ out_ef,
    float* __restrict__ out_elp, int L, int base, int step) {
  const int gw = blockIdx.x * 4 + (threadIdx.x >> 6);
  const int lane = threadIdx.x & 63;
  uint32_t ka0, ka1, kb0, kb1;
  tf2x32(0u, 42u, 0u, (uint32_t)(step * 100 + 50 + 0), ka0, ka1);
  tf2x32(0u, 42u, 0u, (uint32_t)(step * 100 + 50 + 1), kb0, kb1);
  for (int r = gw; r < L * 512; r += 1024) {
    const int tt = r >> 9, b = r & 511;
    const float* row = eout + ((size_t)(L - 1 - tt) * 512 + b) * HDIM;
    const float e0 = row[lane];
    const float e1 = row[lane + 64];
    const float e2 = row[lane + 128];
    const float e3 = row[lane + 192];
    const size_t orow = (size_t)(base + tt) * 512 + b;

    auto phase = [&](const float* W, const float* bb, int nf, uint32_t kk0,
                     uint32_t kk1, int coff, int jidx) {
      float ml = 0.f;
      for (int jf = 0; jf < nf; ++jf) {
        const float* wr = W + (size_t)jf * HDIM;
        float p = e0 * wr[lane] + e1 * wr[lane + 64] + e2 * wr[lane + 128] +
                  e3 * wr[lane + 192];
#pragma unroll
        for (int d = 32; d; d >>= 1) p += __shfl_xor(p, d);
        if (lane == jf) ml = p + bb[jf];
      }
      const bool act = lane < nf;
      float g = act ? gumbel_at(kk0, kk1, (uint32_t)(r * nf + lane)) : 0.f;
      float tv = act ? (ml + g) / 1e-3f : -INFINITY;
      float mx = tv;
#pragma unroll
      for (int d = 32; d; d >>= 1) mx = fmaxf(mx, __shfl_xor(mx, d));
      float e = act ? expf(tv - mx) : 0.f;
      float se = e;
#pragma unroll
      for (int d = 32; d; d >>= 1) se += __shfl_xor(se, d);
      float s = act ? e / se : 0.f;
      float mx2 = act ? s : -INFINITY;
#pragma unroll
      for (int d = 32; d; d >>= 1) mx2 = fmaxf(mx2, __shfl_xor(mx2, d));
      float e2v = act ? expf(s - mx2) : 0.f;
      float se2 = e2v;
#pragma unroll
      for (int d = 32; d; d >>= 1) se2 += __shfl_xor(se2, d);
      float logp = s - mx2 - logf(se2);
      float w = act ? s * logp : 0.f;
#pragma unroll
      for (int d = 32; d; d >>= 1) w += __shfl_xor(w, d);
      if (act) out_ef[orow * 9 + coff + lane] = s;
      if (lane == 0) out_elp[orow * 2 + jidx] = w;
    };
    phase(W0, b0, 5, ka0, ka1, 0, 0);
    phase(W1, b1, 4, kb0, kb1, 5, 1);
  }
}

// ---------------- the fused kernel ----------------
__global__ __launch_bounds__(NTHR)
void fused_rnn(const float* __restrict__ z, const float* __restrict__ lpW,
               const float* __restrict__ lpb, const float* __restrict__ nWih,
               const float* __restrict__ nWhh, const float* __restrict__ nbih,
               const float* __restrict__ nbhh, const float* __restrict__ eWih,
               const float* __restrict__ eWhh, const float* __restrict__ ebih,
               const float* __restrict__ ebhh, const float* __restrict__ ncW0,
               const float* __restrict__ ncb0, const float* __restrict__ ncW1,
               const float* __restrict__ ncb1, const float* __restrict__ ncW2,
               const float* __restrict__ ncb2, const float* __restrict__ ecW0,
               const float* __restrict__ ecb0, const float* __restrict__ ecW1,
               const float* __restrict__ ecb1, float* __restrict__ ws,
               float* __restrict__ out) {
  __shared__ float As[32][68];
  __shared__ float Ws[48][68];

  float* embs  = ws + WS_EMB;
  float* egi   = ws + WS_EGI;
  float* ngi   = ws + WS_NGI;
  float* h0b   = ws + WS_H0;
  float* ehf   = ws + WS_EHF;
  float* eoutb = ws + WS_EOUT;
  float* nn    = ws + WS_NN;
  uint32_t* cnt = (uint32_t*)(ws + WS_CNT);

  float* o_nf = out + O_NF;
  float* o_ef = out + O_EF;
  float* o_nl = out + O_NL;
  float* o_el = out + O_EL;

  const int t  = threadIdx.x;
  const int wg = blockIdx.x;
  uint32_t tgt = 0;

  // ---- P0: init ehf[0], nn, ngi(step0 = bias), latent projection ----
  {
    int gid = wg * NTHR + t;                  // 0..65535
    ehf[gid] = 0.f;
    ehf[gid + 65536] = 0.f;
    if (gid < 512) nn[gid] = -1.f;
    for (int x = gid; x < 393216; x += 65536) ngi[x] = nbih[x % 768];
    for (int m = wg; m < 512; m += NWG) {     // latproj rows
      const float* zr = z + m * 128;
      const float* wr = lpW + t * 128;
      float s = 0.f;
      for (int k = 0; k < 128; ++k) s += zr[k] * wr[k];
      s += lpb[t];
      const float alpha = 1.6732632423543772f, scale = 1.0507009873554805f;
      h0b[(size_t)m * HDIM + t] = scale * (s > 0.f ? s : alpha * expm1f(s));
    }
  }
  gsync(cnt, tgt);

  int ep = 0, base = 0;
  for (int i = 0; i < 50; ++i) {
    float* embi = embs + (size_t)(i & 1) * 131072;
    const float* xprev = embs + (size_t)((i - 1) & 1) * 131072;

    // ---- phase N(i): node GRU step (+ deferred edge_cls(i-1)) ----
    const float* hin  = i ? xprev : h0b;
    const float* hadd = (i >= 2) ? ehf + (size_t)ep * 131072 : nullptr;
    gemm_tile(hin, hadd, nWhh, nbhh, ngi, embi, nullptr, As, Ws);
    if (i >= 2) {
      int Lp = (i - 1) < 12 ? (i - 1) : 12;
      edge_cls_all(eoutb, ecW0, ecb0, ecW1, ecb1, o_ef, o_el, Lp, base - Lp,
                   i - 1);
    }
    gsync(cnt, tgt);

    if (i == 0) {
      // ---- phase C0: node_cls(0), node-gi(1), edge-gi(0) ----
      gemm_tile(embi, nullptr, nWih, nbih, nullptr, ngi, nullptr, As, Ws);
      gemm_tile(embi, nullptr, eWih, ebih, nullptr, egi, nullptr, As, Ws);
      node_cls_all(embi, ncW0, ncb0, ncW1, ncb1, ncW2, ncb2, o_nf, o_nl, nn, 0);
      gsync(cnt, tgt);
    } else {
      int L = i < 12 ? i : 12;
      for (int tt = 0; tt < L; ++tt) {
        const float* hh0 = tt == 0 ? ehf + (size_t)ep * 131072
                                   : eoutb + (size_t)(tt - 1) * 131072;
        const float* hh1 = tt == 0 ? embi : nullptr;
        float* oh = eoutb + (size_t)tt * 131072;
        float* o2 = (tt == L - 1) ? ehf + (size_t)(1 - ep) * 131072 : nullptr;
        gemm_tile(hh0, hh1, eWhh, ebhh,
                  egi + (size_t)((i - 1 - tt) % 13) * 393216, oh, o2, As, Ws);
        if (tt == 0) {
          node_cls_all(embi, ncW0, ncb0, ncW1, ncb1, ncW2, ncb2, o_nf, o_nl,
                       nn, i);
          if (i <= 48) {
            gemm_tile(embi, nullptr, nWih, nbih, nullptr, ngi, nullptr, As, Ws);
            gemm_tile(embi, nullptr, eWih, ebih, nullptr,
                      egi + (size_t)(i % 13) * 393216, nullptr, As, Ws);
          }
        }
        gsync(cnt, tgt);
      }
      ep = 1 - ep;
      base += L;
    }
  }

  // ---- final: edge_cls(49) + num_nodes finalize ----
  edge_cls_all(eoutb, ecW0, ecb0, ecW1, ecb1, o_ef, o_el, 12, 510, 49);
  {
    int gid = wg * NTHR + t;
    if (gid < 512) {
      float v = nn[gid];
      out[gid] = (v == -1.f) ? 50.f : v;
    }
  }
}

// ---------------- host ----------------
extern "C" void kernel_launch(void* const* d_in, const int* in_sizes, int n_in,
                              void* d_out, int out_size, void* d_ws,
                              size_t ws_size, hipStream_t stream) {
  (void)in_sizes; (void)n_in; (void)out_size; (void)ws_size;
  const float* z    = (const float*)d_in[0];
  const float* lpW  = (const float*)d_in[1];
  const float* lpb  = (const float*)d_in[2];
  const float* nWih = (const float*)d_in[3];
  const float* nWhh = (const float*)d_in[4];
  const float* nbih = (const float*)d_in[5];
  const float* nbhh = (const float*)d_in[6];
  const float* eWih = (const float*)d_in[7];
  const float* eWhh = (const float*)d_in[8];
  const float* ebih = (const float*)d_in[9];
  const float* ebhh = (const float*)d_in[10];
  const float* ncW0 = (const float*)d_in[11];
  const float* ncb0 = (const float*)d_in[12];
  const float* ncW1 = (const float*)d_in[13];
  const float* ncb1 = (const float*)d_in[14];
  const float* ncW2 = (const float*)d_in[15];
  const float* ncb2 = (const float*)d_in[16];
  const float* ecW0 = (const float*)d_in[17];
  const float* ecb0 = (const float*)d_in[18];
  const float* ecW1 = (const float*)d_in[19];
  const float* ecb1 = (const float*)d_in[20];

  // zero the barrier counter (ws is NOT re-poisoned between replays)
  hipMemsetAsync((char*)d_ws + (size_t)WS_CNT * 4, 0, 4, stream);

  fused_rnn<<<dim3(NWG), dim3(NTHR), 0, stream>>>(
      z, lpW, lpb, nWih, nWhh, nbih, nbhh, eWih, eWhh, ebih, ebhh, ncW0, ncb0,
      ncW1, ncb1, ncW2, ncb2, ecW0, ecb0, ecW1, ecb1, (float*)d_ws,
      (float*)d_out);
}

// Round 3
// 18455.716 us; speedup vs baseline: 1.0671x; 1.0671x over previous
//
#include <hip/hip_runtime.h>
#include <stdint.h>
#include <math.h>

// ---------------------------------------------------------------------------
// Batch-parallel fused graph-generator RNN (B=512, H=256, 50 steps, window 12)
// KEY: batch rows are fully independent -> NO grid sync. 128 WGs x 512 thr,
// each WG owns NR=4 rows and runs the whole recurrence locally (state in LDS,
// __syncthreads only). Weights stream from L2; edge input-gates precomputed
// into a 13-slot global ring (L3-resident, reused up to 12x).
// All per-output arithmetic (dot k-order, GRU combine, classifier/softmax/
// gumbel) is kept VERBATIM from the passing round-1 kernel.
// ---------------------------------------------------------------------------

#define NWG 128
#define NTHR 512
#define NR 4

// output layout (floats)
#define O_NF 512u              // node feats [512][50][51]
#define O_EF 1306112u          // edge feats [522][512][9]
#define O_NL 3711488u          // node logprobs [512][50][3]
#define O_EL 3788288u          // edge logprobs [522][512][2]

// ---------------- threefry2x32 (exact JAX semantics) ----------------
__host__ __device__ inline void tf2x32(uint32_t k0, uint32_t k1,
                                       uint32_t x0, uint32_t x1,
                                       uint32_t& o0, uint32_t& o1) {
  uint32_t ks2 = k0 ^ k1 ^ 0x1BD11BDAu;
#define TFR(r) { x0 += x1; x1 = (x1 << r) | (x1 >> (32 - r)); x1 ^= x0; }
  x0 += k0; x1 += k1;
  TFR(13) TFR(15) TFR(26) TFR(6)
  x0 += k1; x1 += ks2 + 1u;
  TFR(17) TFR(29) TFR(16) TFR(24)
  x0 += ks2; x1 += k0 + 2u;
  TFR(13) TFR(15) TFR(26) TFR(6)
  x0 += k0; x1 += k1 + 3u;
  TFR(17) TFR(29) TFR(16) TFR(24)
  x0 += k1; x1 += ks2 + 4u;
  TFR(13) TFR(15) TFR(26) TFR(6)
  x0 += ks2; x1 += k0 + 5u;
#undef TFR
  o0 = x0; o1 = x1;
}

__device__ inline float gumbel_at(uint32_t k0, uint32_t k1, uint32_t idx) {
  uint32_t o0, o1;
  tf2x32(k0, k1, 0u, idx, o0, o1);
  uint32_t bits = o0 ^ o1;
  float u = __uint_as_float((bits >> 9) | 0x3f800000u) - 1.0f;
  u = fmaxf(u, 1.1754943508222875e-38f);
  return -logf(-logf(u));
}

// ---------------- 768x256 GEMV over LDS x (verbatim dot order) --------------
// t < 256 : outputs o = t (gate0) and o = 512+t (gate2)  -> a0[], a2[]
// t >= 256: output  o = t (gate1, col t-256)             -> a0[]
__device__ __forceinline__ void gemv768(const float* __restrict__ W,
                                        const float (*__restrict__ x)[256],
                                        int t, float a0[NR], float a2[NR]) {
  const float* w1 = W + (size_t)t * 256;
#pragma unroll
  for (int r = 0; r < NR; ++r) { a0[r] = 0.f; a2[r] = 0.f; }
  if (t < 256) {
    const float* w2 = W + (size_t)(512 + t) * 256;
    for (int k0 = 0; k0 < 256; k0 += 32) {
      float4 wa[8], wb[8];
#pragma unroll
      for (int u = 0; u < 8; ++u) wa[u] = *(const float4*)(w1 + k0 + 4 * u);
#pragma unroll
      for (int u = 0; u < 8; ++u) wb[u] = *(const float4*)(w2 + k0 + 4 * u);
#pragma unroll
      for (int u = 0; u < 8; ++u) {
#pragma unroll
        for (int r = 0; r < NR; ++r) {
          const float4 hx = *(const float4*)&x[r][k0 + 4 * u];
          const float4 wv = wa[u];
          const float4 wv2 = wb[u];
          a0[r] += hx.x * wv.x + hx.y * wv.y + hx.z * wv.z + hx.w * wv.w;
          a2[r] += hx.x * wv2.x + hx.y * wv2.y + hx.z * wv2.z + hx.w * wv2.w;
        }
      }
    }
  } else {
    for (int k0 = 0; k0 < 256; k0 += 32) {
      float4 wa[8];
#pragma unroll
      for (int u = 0; u < 8; ++u) wa[u] = *(const float4*)(w1 + k0 + 4 * u);
#pragma unroll
      for (int u = 0; u < 8; ++u) {
#pragma unroll
        for (int r = 0; r < NR; ++r) {
          const float4 hx = *(const float4*)&x[r][k0 + 4 * u];
          const float4 wv = wa[u];
          a0[r] += hx.x * wv.x + hx.y * wv.y + hx.z * wv.z + hx.w * wv.w;
        }
      }
    }
  }
}

// ---------------- node classifier phase (verbatim round-1) ----------------
__device__ __forceinline__ void node_phase(
    float e0, float e1, float e2, float e3, int lane, int b, int step,
    const float* __restrict__ W, const float* __restrict__ bb, int nf,
    uint32_t kk0, uint32_t kk1, int coff, int jidx, bool do_arg,
    float* __restrict__ o_nf, float* __restrict__ o_nl,
    float* __restrict__ nnrow) {
  float ml = 0.f;
  for (int jf = 0; jf < nf; ++jf) {
    const float* wr = W + (size_t)jf * 256;
    float p = e0 * wr[lane] + e1 * wr[lane + 64] + e2 * wr[lane + 128] +
              e3 * wr[lane + 192];
#pragma unroll
    for (int d = 32; d; d >>= 1) p += __shfl_xor(p, d);
    if (lane == jf) ml = p + bb[jf];
  }
  const bool act = lane < nf;
  float g = act ? gumbel_at(kk0, kk1, (uint32_t)(b * nf + lane)) : 0.f;
  float tv = act ? (ml + g) / 1e-3f : -INFINITY;
  float mx = tv;
#pragma unroll
  for (int d = 32; d; d >>= 1) mx = fmaxf(mx, __shfl_xor(mx, d));
  float e = act ? expf(tv - mx) : 0.f;
  float se = e;
#pragma unroll
  for (int d = 32; d; d >>= 1) se += __shfl_xor(se, d);
  float s = act ? e / se : 0.f;
  float mx2 = act ? ml : -INFINITY;
#pragma unroll
  for (int d = 32; d; d >>= 1) mx2 = fmaxf(mx2, __shfl_xor(mx2, d));
  float e2v = act ? expf(ml - mx2) : 0.f;
  float se2 = e2v;
#pragma unroll
  for (int d = 32; d; d >>= 1) se2 += __shfl_xor(se2, d);
  float logp = ml - mx2 - logf(se2);
  float w = act ? s * logp : 0.f;
#pragma unroll
  for (int d = 32; d; d >>= 1) w += __shfl_xor(w, d);
  if (act) o_nf[((size_t)b * 50 + step) * 51 + coff + lane] = s;
  if (lane == 0) o_nl[((size_t)b * 50 + step) * 3 + jidx] = w;
  if (do_arg) {
    float av = act ? s : -1.f;
    int ai = lane;
#pragma unroll
    for (int d = 32; d; d >>= 1) {
      float ov = __shfl_xor(av, d);
      int oi = __shfl_xor(ai, d);
      if (ov > av || (ov == av && oi < ai)) { av = ov; ai = oi; }
    }
    if (lane == 0 && ai == 39 && nnrow[0] == -1.0f)
      nnrow[0] = (float)(step + 1);
  }
}

// ---------------- edge classifier phase (verbatim round-1) ----------------
__device__ __forceinline__ void edge_phase(
    float e0, float e1, float e2, float e3, int lane, int ridx, size_t orow,
    const float* __restrict__ W, const float* __restrict__ bb, int nf,
    uint32_t kk0, uint32_t kk1, int coff, int jidx,
    float* __restrict__ o_ef, float* __restrict__ o_el) {
  float ml = 0.f;
  for (int jf = 0; jf < nf; ++jf) {
    const float* wr = W + (size_t)jf * 256;
    float p = e0 * wr[lane] + e1 * wr[lane + 64] + e2 * wr[lane + 128] +
              e3 * wr[lane + 192];
#pragma unroll
    for (int d = 32; d; d >>= 1) p += __shfl_xor(p, d);
    if (lane == jf) ml = p + bb[jf];
  }
  const bool act = lane < nf;
  float g = act ? gumbel_at(kk0, kk1, (uint32_t)(ridx * nf + lane)) : 0.f;
  float tv = act ? (ml + g) / 1e-3f : -INFINITY;
  float mx = tv;
#pragma unroll
  for (int d = 32; d; d >>= 1) mx = fmaxf(mx, __shfl_xor(mx, d));
  float e = act ? expf(tv - mx) : 0.f;
  float se = e;
#pragma unroll
  for (int d = 32; d; d >>= 1) se += __shfl_xor(se, d);
  float s = act ? e / se : 0.f;
  // NOTE: edge path takes log_softmax of the SAMPLES (faithful to source)
  float mx2 = act ? s : -INFINITY;
#pragma unroll
  for (int d = 32; d; d >>= 1) mx2 = fmaxf(mx2, __shfl_xor(mx2, d));
  float e2v = act ? expf(s - mx2) : 0.f;
  float se2 = e2v;
#pragma unroll
  for (int d = 32; d; d >>= 1) se2 += __shfl_xor(se2, d);
  float logp = s - mx2 - logf(se2);
  float w = act ? s * logp : 0.f;
#pragma unroll
  for (int d = 32; d; d >>= 1) w += __shfl_xor(w, d);
  if (act) o_ef[orow * 9 + coff + lane] = s;
  if (lane == 0) o_el[orow * 2 + jidx] = w;
}

// ---------------- the fused kernel ----------------
__global__ __launch_bounds__(NTHR)
void fused_rnn(const float* __restrict__ z, const float* __restrict__ lpW,
               const float* __restrict__ lpb, const float* __restrict__ nWih,
               const float* __restrict__ nWhh, const float* __restrict__ nbih,
               const float* __restrict__ nbhh, const float* __restrict__ eWih,
               const float* __restrict__ eWhh, const float* __restrict__ ebih,
               const float* __restrict__ ebhh, const float* __restrict__ ncW0,
               const float* __restrict__ ncb0, const float* __restrict__ ncW1,
               const float* __restrict__ ncb1, const float* __restrict__ ncW2,
               const float* __restrict__ ncb2, const float* __restrict__ ecW0,
               const float* __restrict__ ecb0, const float* __restrict__ ecW1,
               const float* __restrict__ ecb1, float* __restrict__ egi_ws,
               float* __restrict__ out) {
  __shared__ float xb[2][NR][256];   // node_emb ping-pong (emb[i], emb[i-1])
  __shared__ float he[NR][256];      // edge_h (persistent)
  __shared__ float ht[NR][256];      // node hidden input / latproj h0
  __shared__ float ngiL[NR][768];    // node input gates
  __shared__ float nex[NR][256];     // gate-z exchange
  __shared__ float nnL[NR];          // num_nodes

  const int t = threadIdx.x;
  const int wg = blockIdx.x;
  const int b0 = wg * NR;
  float* egi = egi_ws + (size_t)wg * (13u * NR * 768u);

  float* o_nf = out + O_NF;
  float* o_ef = out + O_EF;
  float* o_nl = out + O_NL;
  float* o_el = out + O_EL;

  // ---- init: he=0, nn=-1, ngi = bias (step-0 gi has x=0), latproj -> ht ----
  for (int x = t; x < NR * 256; x += NTHR) ((float*)he)[x] = 0.f;
  if (t < NR) nnL[t] = -1.f;
  for (int x = t; x < NR * 768; x += NTHR) ((float*)ngiL)[x] = nbih[x % 768];
  if (t < 256) {
    const float* wr = lpW + (size_t)t * 128;
    const float alpha = 1.6732632423543772f, scale = 1.0507009873554805f;
    for (int r = 0; r < NR; ++r) {
      const float* zr = z + (size_t)(b0 + r) * 128;
      float s = 0.f;
      for (int k = 0; k < 128; ++k) s += zr[k] * wr[k];
      s += lpb[t];
      ht[r][t] = scale * (s > 0.f ? s : alpha * expm1f(s));
    }
  }
  __syncthreads();

  int base = 0;
  for (int i = 0; i < 50; ++i) {
    const int cur = i & 1, prv = cur ^ 1;

    if (i >= 1) {
      // ht = emb[i-1] (+ edge_h for i>=2);  ngi = emb[i-1] @ nWih.T + nbih
      for (int x = t; x < NR * 256; x += NTHR) {
        float v = ((float*)xb[prv])[x];
        if (i >= 2) v += ((float*)he)[x];
        ((float*)ht)[x] = v;
      }
      float a0[NR], a2[NR];
      gemv768(nWih, xb[prv], t, a0, a2);
      if (t < 256) {
#pragma unroll
        for (int r = 0; r < NR; ++r) {
          ngiL[r][t] = a0[r] + nbih[t];
          ngiL[r][512 + t] = a2[r] + nbih[512 + t];
        }
      } else {
#pragma unroll
        for (int r = 0; r < NR; ++r) ngiL[r][t] = a0[r] + nbih[t];
      }
      __syncthreads();
    }

    // ---- node GRU: gh = ht @ nWhh.T + nbhh; combine -> emb[i] = xb[cur] ----
    {
      float a0[NR], a2[NR];
      gemv768(nWhh, ht, t, a0, a2);
      if (t >= 256) {
        const int c = t - 256;
#pragma unroll
        for (int r = 0; r < NR; ++r) nex[r][c] = a0[r] + nbhh[256 + c];
      }
      __syncthreads();
      if (t < 256) {
#pragma unroll
        for (int r = 0; r < NR; ++r) {
          float hr = a0[r] + nbhh[t];
          float hn = a2[r] + nbhh[512 + t];
          float hz = nex[r][t];
          float ir = ngiL[r][t], iz = ngiL[r][256 + t], inn = ngiL[r][512 + t];
          float h = ht[r][t];
          float rr = 1.f / (1.f + expf(-(ir + hr)));
          float zg = 1.f / (1.f + expf(-(iz + hz)));
          float n = tanhf(inn + rr * hn);
          xb[cur][r][t] = (1.f - zg) * n + zg * h;
        }
      }
      __syncthreads();
    }

    // ---- edge input gates for emb[i] -> global ring slot i%13 ----
    if (i <= 48) {
      float a0[NR], a2[NR];
      gemv768(eWih, xb[cur], t, a0, a2);
      float* eg = egi + (size_t)(i % 13) * (NR * 768);
      if (t < 256) {
#pragma unroll
        for (int r = 0; r < NR; ++r) {
          eg[r * 768 + t] = a0[r] + ebih[t];
          eg[r * 768 + 512 + t] = a2[r] + ebih[512 + t];
        }
      } else {
#pragma unroll
        for (int r = 0; r < NR; ++r) eg[r * 768 + t] = a0[r] + ebih[t];
      }
    }

    // ---- node classifiers + sampling (waves over rows) ----
    {
      const int w = t >> 6, lane = t & 63, row = w & 3, b = b0 + row;
      const float e0 = xb[cur][row][lane];
      const float e1 = xb[cur][row][lane + 64];
      const float e2 = xb[cur][row][lane + 128];
      const float e3 = xb[cur][row][lane + 192];
      uint32_t k0_, k1_;
      if (w < 4) {
        tf2x32(0u, 42u, 0u, (uint32_t)(i * 100 + 0), k0_, k1_);
        node_phase(e0, e1, e2, e3, lane, b, i, ncW0, ncb0, 40, k0_, k1_, 0, 0,
                   true, o_nf, o_nl, &nnL[row]);
      } else {
        tf2x32(0u, 42u, 0u, (uint32_t)(i * 100 + 1), k0_, k1_);
        node_phase(e0, e1, e2, e3, lane, b, i, ncW1, ncb1, 6, k0_, k1_, 40, 1,
                   false, o_nf, o_nl, &nnL[row]);
        tf2x32(0u, 42u, 0u, (uint32_t)(i * 100 + 2), k0_, k1_);
        node_phase(e0, e1, e2, e3, lane, b, i, ncW2, ncb2, 5, k0_, k1_, 46, 2,
                   false, o_nf, o_nl, &nnL[row]);
      }
    }

    // ---- edge scan ----
    if (i >= 1) {
      const int L = i < 12 ? i : 12;
      // edge_h += node_h
      for (int x = t; x < NR * 256; x += NTHR)
        ((float*)he)[x] += ((float*)xb[cur])[x];
      __syncthreads();
      uint32_t ea0, ea1, eb0, eb1;
      tf2x32(0u, 42u, 0u, (uint32_t)(i * 100 + 50), ea0, ea1);
      tf2x32(0u, 42u, 0u, (uint32_t)(i * 100 + 51), eb0, eb1);
      for (int s = 0; s < L; ++s) {
        const int xs = (i - 1 - s) % 13;
        float a0[NR], a2[NR];
        gemv768(eWhh, he, t, a0, a2);
        if (t >= 256) {
          const int c = t - 256;
#pragma unroll
          for (int r = 0; r < NR; ++r) nex[r][c] = a0[r] + ebhh[256 + c];
        }
        __syncthreads();
        if (t < 256) {
          const float* eg = egi + (size_t)xs * (NR * 768);
#pragma unroll
          for (int r = 0; r < NR; ++r) {
            float hr = a0[r] + ebhh[t];
            float hn = a2[r] + ebhh[512 + t];
            float hz = nex[r][t];
            float ir = eg[r * 768 + t];
            float iz = eg[r * 768 + 256 + t];
            float inn = eg[r * 768 + 512 + t];
            float h = he[r][t];
            float rr = 1.f / (1.f + expf(-(ir + hr)));
            float zg = 1.f / (1.f + expf(-(iz + hz)));
            float n = tanhf(inn + rr * hn);
            he[r][t] = (1.f - zg) * n + zg * h;
          }
        }
        __syncthreads();
        // edge classifiers on h2 = he (scan step s -> output row L-1-s)
        {
          const int w = t >> 6, lane = t & 63, row = w & 3, b = b0 + row;
          const int tt = L - 1 - s;
          const int ridx = tt * 512 + b;
          const size_t orow = (size_t)(base + tt) * 512 + b;
          const float e0 = he[row][lane];
          const float e1 = he[row][lane + 64];
          const float e2 = he[row][lane + 128];
          const float e3 = he[row][lane + 192];
          if (w < 4)
            edge_phase(e0, e1, e2, e3, lane, ridx, orow, ecW0, ecb0, 5, ea0,
                       ea1, 0, 0, o_ef, o_el);
          else
            edge_phase(e0, e1, e2, e3, lane, ridx, orow, ecW1, ecb1, 4, eb0,
                       eb1, 5, 1, o_ef, o_el);
        }
      }
      base += L;
    }
    __syncthreads();
  }

  // ---- finalize num_nodes ----
  if (t < NR) {
    float v = nnL[t];
    out[b0 + t] = (v == -1.f) ? 50.f : v;
  }
}

// ---------------- host ----------------
extern "C" void kernel_launch(void* const* d_in, const int* in_sizes, int n_in,
                              void* d_out, int out_size, void* d_ws,
                              size_t ws_size, hipStream_t stream) {
  (void)in_sizes; (void)n_in; (void)out_size; (void)ws_size;
  const float* z    = (const float*)d_in[0];
  const float* lpW  = (const float*)d_in[1];
  const float* lpb  = (const float*)d_in[2];
  const float* nWih = (const float*)d_in[3];
  const float* nWhh = (const float*)d_in[4];
  const float* nbih = (const float*)d_in[5];
  const float* nbhh = (const float*)d_in[6];
  const float* eWih = (const float*)d_in[7];
  const float* eWhh = (const float*)d_in[8];
  const float* ebih = (const float*)d_in[9];
  const float* ebhh = (const float*)d_in[10];
  const float* ncW0 = (const float*)d_in[11];
  const float* ncb0 = (const float*)d_in[12];
  const float* ncW1 = (const float*)d_in[13];
  const float* ncb1 = (const float*)d_in[14];
  const float* ncW2 = (const float*)d_in[15];
  const float* ncb2 = (const float*)d_in[16];
  const float* ecW0 = (const float*)d_in[17];
  const float* ecb0 = (const float*)d_in[18];
  const float* ecW1 = (const float*)d_in[19];
  const float* ecb1 = (const float*)d_in[20];

  fused_rnn<<<dim3(NWG), dim3(NTHR), 0, stream>>>(
      z, lpW, lpb, nWih, nWhh, nbih, nbhh, eWih, eWhh, ebih, ebhh, ncW0, ncb0,
      ncW1, ncb1, ncW2, ncb2, ecW0, ecb0, ecW1, ecb1, (float*)d_ws,
      (float*)d_out);
}

// Round 4
// 17495.657 us; speedup vs baseline: 1.1256x; 1.0549x over previous
//
#include <hip/hip_runtime.h>
#include <stdint.h>
#include <math.h>

// ---------------------------------------------------------------------------
// Batch-parallel fused graph-generator RNN (B=512, H=256, 50 steps, window 12)
// Round-4: coalesced GEMV via pre-transposed weight layout W4[kg][768]xfloat4
// (setup kernel), thread t owns all 3 gates of column t (no LDS exchange),
// fused gi+gh node pass, register prefetch. Per-output arithmetic (dot
// k-order, GRU combine, classifier/softmax/gumbel) VERBATIM from the passing
// round-1/3 kernels => bit-identical outputs.
// ---------------------------------------------------------------------------

#define NR 4
#define NWG 128
#define NTHR 256
#define KGP 66                 // 64 kg rows + 2 pad (prefetch overrun)
#define MATS 50688u            // KGP*768 float4s per matrix
#define MATF 202752u           // floats per matrix

// ws layout (floats)
#define WS_W4   0u             // 4 * 202752 = 811008
#define WS_H0   811008u        // 131072
#define WS_EGI  942080u        // 128 * 13 * 4 * 768 = 5111808
// total 6053888 floats = 24.2 MB

// output layout (floats)
#define O_NF 512u              // node feats [512][50][51]
#define O_EF 1306112u          // edge feats [522][512][9]
#define O_NL 3711488u          // node logprobs [512][50][3]
#define O_EL 3788288u          // edge logprobs [522][512][2]

// ---------------- threefry2x32 (exact JAX semantics) ----------------
__host__ __device__ inline void tf2x32(uint32_t k0, uint32_t k1,
                                       uint32_t x0, uint32_t x1,
                                       uint32_t& o0, uint32_t& o1) {
  uint32_t ks2 = k0 ^ k1 ^ 0x1BD11BDAu;
#define TFR(r) { x0 += x1; x1 = (x1 << r) | (x1 >> (32 - r)); x1 ^= x0; }
  x0 += k0; x1 += k1;
  TFR(13) TFR(15) TFR(26) TFR(6)
  x0 += k1; x1 += ks2 + 1u;
  TFR(17) TFR(29) TFR(16) TFR(24)
  x0 += ks2; x1 += k0 + 2u;
  TFR(13) TFR(15) TFR(26) TFR(6)
  x0 += k0; x1 += k1 + 3u;
  TFR(17) TFR(29) TFR(16) TFR(24)
  x0 += k1; x1 += ks2 + 4u;
  TFR(13) TFR(15) TFR(26) TFR(6)
  x0 += ks2; x1 += k0 + 5u;
#undef TFR
  o0 = x0; o1 = x1;
}

__device__ inline float gumbel_at(uint32_t k0, uint32_t k1, uint32_t idx) {
  uint32_t o0, o1;
  tf2x32(k0, k1, 0u, idx, o0, o1);
  uint32_t bits = o0 ^ o1;
  float u = __uint_as_float((bits >> 9) | 0x3f800000u) - 1.0f;
  u = fmaxf(u, 1.1754943508222875e-38f);
  return -logf(-logf(u));
}

// ---------------- setup kernel: W transpose + latproj ----------------
// grid 832 x 256. WGs 0..767: transpose 4 matrices into W4 layout
// W4q[mat*MATS + kg*768 + o] = (float4)W[o*256 + 4kg]. WGs 768..831: latproj.
__global__ __launch_bounds__(256)
void setup_k(const float* __restrict__ nWih, const float* __restrict__ nWhh,
             const float* __restrict__ eWih, const float* __restrict__ eWhh,
             const float* __restrict__ z, const float* __restrict__ lpW,
             const float* __restrict__ lpb, float* __restrict__ ws) {
  const int wg = blockIdx.x, t = threadIdx.x;
  if (wg < 768) {
    int gid = wg * 256 + t;                 // 0..196607
    int mat = gid / 49152;
    int rem = gid - mat * 49152;
    int kg = rem / 768;
    int o = rem - kg * 768;
    const float* src = (mat == 0) ? nWih : (mat == 1) ? nWhh
                       : (mat == 2) ? eWih : eWhh;
    float4 v = *(const float4*)(src + (size_t)o * 256 + kg * 4);
    ((float4*)(ws + WS_W4))[(size_t)mat * MATS + (size_t)kg * 768 + o] = v;
  } else {
    float* h0 = ws + WS_H0;
    int idx = (wg - 768) * 256 + t;         // 0..16383
    const float alpha = 1.6732632423543772f, scale = 1.0507009873554805f;
    for (int q = 0; q < 8; ++q) {
      int flat = idx + q * 16384;           // 0..131071
      int m = flat >> 8, j = flat & 255;
      const float* zr = z + (size_t)m * 128;
      const float* wr = lpW + (size_t)j * 128;
      float s = 0.f;
      for (int k = 0; k < 128; ++k) s += zr[k] * wr[k];
      s += lpb[j];
      h0[(size_t)m * 256 + j] = scale * (s > 0.f ? s : alpha * expm1f(s));
    }
  }
}

// ---------------- coalesced 3-gate GEMV (dist-2 prefetch) ----------------
// a[g][r] = sum_k W[g*256+t][k] * x[r][k], verbatim float4 dot order.
__device__ __forceinline__ void gemv3(const float4* __restrict__ Wq,
                                      const float (*__restrict__ x)[256],
                                      int t, float a[3][NR]) {
#pragma unroll
  for (int g = 0; g < 3; ++g)
#pragma unroll
    for (int r = 0; r < NR; ++r) a[g][r] = 0.f;
  float4 c0 = Wq[t], c1 = Wq[256 + t], c2 = Wq[512 + t];
  float4 d0 = Wq[768 + t], d1 = Wq[768 + 256 + t], d2 = Wq[768 + 512 + t];
  for (int kg = 0; kg < 64; ++kg) {
#pragma unroll
    for (int r = 0; r < NR; ++r) {
      const float4 xv = *(const float4*)&x[r][kg * 4];
      a[0][r] += xv.x * c0.x + xv.y * c0.y + xv.z * c0.z + xv.w * c0.w;
      a[1][r] += xv.x * c1.x + xv.y * c1.y + xv.z * c1.z + xv.w * c1.w;
      a[2][r] += xv.x * c2.x + xv.y * c2.y + xv.z * c2.z + xv.w * c2.w;
    }
    c0 = d0; c1 = d1; c2 = d2;
    const float4* nx = Wq + (size_t)(kg + 2) * 768;   // kg+2 <= 65 (pad)
    d0 = nx[t]; d1 = nx[256 + t]; d2 = nx[512 + t];
  }
}

// ---------------- fused dual 3-gate GEMV (dist-1 prefetch) ----------------
__device__ __forceinline__ void gemv6(const float4* __restrict__ Wa,
                                      const float4* __restrict__ Wb,
                                      const float (*__restrict__ xa)[256],
                                      const float (*__restrict__ xh)[256],
                                      int t, float ga[3][NR], float gb[3][NR]) {
#pragma unroll
  for (int g = 0; g < 3; ++g)
#pragma unroll
    for (int r = 0; r < NR; ++r) { ga[g][r] = 0.f; gb[g][r] = 0.f; }
  float4 cA0 = Wa[t], cA1 = Wa[256 + t], cA2 = Wa[512 + t];
  float4 cB0 = Wb[t], cB1 = Wb[256 + t], cB2 = Wb[512 + t];
  for (int kg = 0; kg < 64; ++kg) {
    const float4* na = Wa + (size_t)(kg + 1) * 768;   // kg+1 <= 64 (pad)
    const float4* nb = Wb + (size_t)(kg + 1) * 768;
    float4 dA0 = na[t], dA1 = na[256 + t], dA2 = na[512 + t];
    float4 dB0 = nb[t], dB1 = nb[256 + t], dB2 = nb[512 + t];
#pragma unroll
    for (int r = 0; r < NR; ++r) {
      const float4 xv = *(const float4*)&xa[r][kg * 4];
      const float4 hv = *(const float4*)&xh[r][kg * 4];
      ga[0][r] += xv.x * cA0.x + xv.y * cA0.y + xv.z * cA0.z + xv.w * cA0.w;
      ga[1][r] += xv.x * cA1.x + xv.y * cA1.y + xv.z * cA1.z + xv.w * cA1.w;
      ga[2][r] += xv.x * cA2.x + xv.y * cA2.y + xv.z * cA2.z + xv.w * cA2.w;
      gb[0][r] += hv.x * cB0.x + hv.y * cB0.y + hv.z * cB0.z + hv.w * cB0.w;
      gb[1][r] += hv.x * cB1.x + hv.y * cB1.y + hv.z * cB1.z + hv.w * cB1.w;
      gb[2][r] += hv.x * cB2.x + hv.y * cB2.y + hv.z * cB2.z + hv.w * cB2.w;
    }
    cA0 = dA0; cA1 = dA1; cA2 = dA2;
    cB0 = dB0; cB1 = dB1; cB2 = dB2;
  }
}

// ---------------- node classifier phase (verbatim round-1) ----------------
__device__ __forceinline__ void node_phase(
    float e0, float e1, float e2, float e3, int lane, int b, int step,
    const float* __restrict__ W, const float* __restrict__ bb, int nf,
    uint32_t kk0, uint32_t kk1, int coff, int jidx, bool do_arg,
    float* __restrict__ o_nf, float* __restrict__ o_nl,
    float* __restrict__ nnrow) {
  float ml = 0.f;
  for (int jf = 0; jf < nf; ++jf) {
    const float* wr = W + (size_t)jf * 256;
    float p = e0 * wr[lane] + e1 * wr[lane + 64] + e2 * wr[lane + 128] +
              e3 * wr[lane + 192];
#pragma unroll
    for (int d = 32; d; d >>= 1) p += __shfl_xor(p, d);
    if (lane == jf) ml = p + bb[jf];
  }
  const bool act = lane < nf;
  float g = act ? gumbel_at(kk0, kk1, (uint32_t)(b * nf + lane)) : 0.f;
  float tv = act ? (ml + g) / 1e-3f : -INFINITY;
  float mx = tv;
#pragma unroll
  for (int d = 32; d; d >>= 1) mx = fmaxf(mx, __shfl_xor(mx, d));
  float e = act ? expf(tv - mx) : 0.f;
  float se = e;
#pragma unroll
  for (int d = 32; d; d >>= 1) se += __shfl_xor(se, d);
  float s = act ? e / se : 0.f;
  float mx2 = act ? ml : -INFINITY;
#pragma unroll
  for (int d = 32; d; d >>= 1) mx2 = fmaxf(mx2, __shfl_xor(mx2, d));
  float e2v = act ? expf(ml - mx2) : 0.f;
  float se2 = e2v;
#pragma unroll
  for (int d = 32; d; d >>= 1) se2 += __shfl_xor(se2, d);
  float logp = ml - mx2 - logf(se2);
  float w = act ? s * logp : 0.f;
#pragma unroll
  for (int d = 32; d; d >>= 1) w += __shfl_xor(w, d);
  if (act) o_nf[((size_t)b * 50 + step) * 51 + coff + lane] = s;
  if (lane == 0) o_nl[((size_t)b * 50 + step) * 3 + jidx] = w;
  if (do_arg) {
    float av = act ? s : -1.f;
    int ai = lane;
#pragma unroll
    for (int d = 32; d; d >>= 1) {
      float ov = __shfl_xor(av, d);
      int oi = __shfl_xor(ai, d);
      if (ov > av || (ov == av && oi < ai)) { av = ov; ai = oi; }
    }
    if (lane == 0 && ai == 39 && nnrow[0] == -1.0f)
      nnrow[0] = (float)(step + 1);
  }
}

// ---------------- edge classifier phase (verbatim round-1) ----------------
__device__ __forceinline__ void edge_phase(
    float e0, float e1, float e2, float e3, int lane, int ridx, size_t orow,
    const float* __restrict__ W, const float* __restrict__ bb, int nf,
    uint32_t kk0, uint32_t kk1, int coff, int jidx,
    float* __restrict__ o_ef, float* __restrict__ o_el) {
  float ml = 0.f;
  for (int jf = 0; jf < nf; ++jf) {
    const float* wr = W + (size_t)jf * 256;
    float p = e0 * wr[lane] + e1 * wr[lane + 64] + e2 * wr[lane + 128] +
              e3 * wr[lane + 192];
#pragma unroll
    for (int d = 32; d; d >>= 1) p += __shfl_xor(p, d);
    if (lane == jf) ml = p + bb[jf];
  }
  const bool act = lane < nf;
  float g = act ? gumbel_at(kk0, kk1, (uint32_t)(ridx * nf + lane)) : 0.f;
  float tv = act ? (ml + g) / 1e-3f : -INFINITY;
  float mx = tv;
#pragma unroll
  for (int d = 32; d; d >>= 1) mx = fmaxf(mx, __shfl_xor(mx, d));
  float e = act ? expf(tv - mx) : 0.f;
  float se = e;
#pragma unroll
  for (int d = 32; d; d >>= 1) se += __shfl_xor(se, d);
  float s = act ? e / se : 0.f;
  // NOTE: edge path takes log_softmax of the SAMPLES (faithful to source)
  float mx2 = act ? s : -INFINITY;
#pragma unroll
  for (int d = 32; d; d >>= 1) mx2 = fmaxf(mx2, __shfl_xor(mx2, d));
  float e2v = act ? expf(s - mx2) : 0.f;
  float se2 = e2v;
#pragma unroll
  for (int d = 32; d; d >>= 1) se2 += __shfl_xor(se2, d);
  float logp = s - mx2 - logf(se2);
  float w = act ? s * logp : 0.f;
#pragma unroll
  for (int d = 32; d; d >>= 1) w += __shfl_xor(w, d);
  if (act) o_ef[orow * 9 + coff + lane] = s;
  if (lane == 0) o_el[orow * 2 + jidx] = w;
}

// ---------------- the fused kernel ----------------
__global__ __launch_bounds__(NTHR, 1)
void fused_rnn(const float* __restrict__ nbih, const float* __restrict__ nbhh,
               const float* __restrict__ ebih, const float* __restrict__ ebhh,
               const float* __restrict__ ncW0, const float* __restrict__ ncb0,
               const float* __restrict__ ncW1, const float* __restrict__ ncb1,
               const float* __restrict__ ncW2, const float* __restrict__ ncb2,
               const float* __restrict__ ecW0, const float* __restrict__ ecb0,
               const float* __restrict__ ecW1, const float* __restrict__ ecb1,
               float* __restrict__ ws, float* __restrict__ out) {
  __shared__ float xb[2][NR][256];   // node_emb ping-pong
  __shared__ float ht[NR][256];      // node hidden input
  __shared__ float he[NR][256];      // edge_h
  __shared__ float nnL[NR];

  const int t = threadIdx.x;
  const int wg = blockIdx.x;
  const int b0 = wg * NR;

  const float4* W4q = (const float4*)(ws + WS_W4);
  const float4* Wih4 = W4q;                 // node Wih
  const float4* Whh4 = W4q + MATS;          // node Whh
  const float4* Eih4 = W4q + 2 * MATS;      // edge Wih
  const float4* Ehh4 = W4q + 3 * MATS;      // edge Whh
  const float* h0 = ws + WS_H0;
  float* egi = ws + WS_EGI + (size_t)wg * (13u * NR * 768u);

  float* o_nf = out + O_NF;
  float* o_ef = out + O_EF;
  float* o_nl = out + O_NL;
  float* o_el = out + O_EL;

  // bias registers
  const float nbih0 = nbih[t], nbih1 = nbih[256 + t], nbih2 = nbih[512 + t];
  const float nbhh0 = nbhh[t], nbhh1 = nbhh[256 + t], nbhh2 = nbhh[512 + t];
  const float ebih0 = ebih[t], ebih1 = ebih[256 + t], ebih2 = ebih[512 + t];
  const float ebhh0 = ebhh[t], ebhh1 = ebhh[256 + t], ebhh2 = ebhh[512 + t];

  // init
#pragma unroll
  for (int r = 0; r < NR; ++r) {
    he[r][t] = 0.f;
    ht[r][t] = h0[(size_t)(b0 + r) * 256 + t];
  }
  if (t < NR) nnL[t] = -1.f;
  __syncthreads();

  int base = 0;
  for (int i = 0; i < 50; ++i) {
    const int cur = i & 1, prv = cur ^ 1;

    // ---- node hidden input ht = emb[i-1] (+ he for i>=2) ----
    if (i >= 1) {
#pragma unroll
      for (int r = 0; r < NR; ++r) {
        float v = xb[prv][r][t];
        if (i >= 2) v += he[r][t];
        ht[r][t] = v;
      }
      __syncthreads();
    }

    // ---- node GRU: fused gi (over emb[i-1]) + gh (over ht) ----
    {
      float gi[3][NR], gh[3][NR];
      if (i >= 1) {
        gemv6(Wih4, Whh4, xb[prv], ht, t, gi, gh);
      } else {
        gemv3(Whh4, ht, t, gh);
#pragma unroll
        for (int g = 0; g < 3; ++g)
#pragma unroll
          for (int r = 0; r < NR; ++r) gi[g][r] = 0.f;
      }
#pragma unroll
      for (int r = 0; r < NR; ++r) {
        float ir  = gi[0][r] + nbih0;
        float iz  = gi[1][r] + nbih1;
        float inn = gi[2][r] + nbih2;
        float hr = gh[0][r] + nbhh0;
        float hz = gh[1][r] + nbhh1;
        float hn = gh[2][r] + nbhh2;
        float h = ht[r][t];
        float rr = 1.f / (1.f + expf(-(ir + hr)));
        float zg = 1.f / (1.f + expf(-(iz + hz)));
        float n = tanhf(inn + rr * hn);
        xb[cur][r][t] = (1.f - zg) * n + zg * h;
      }
      __syncthreads();
    }

    // ---- edge input gates for emb[i] -> global ring slot i%13 ----
    if (i <= 48) {
      float a[3][NR];
      gemv3(Eih4, xb[cur], t, a);
      float* eg = egi + (size_t)(i % 13) * (NR * 768);
#pragma unroll
      for (int r = 0; r < NR; ++r) {
        eg[r * 768 + t] = a[0][r] + ebih0;
        eg[r * 768 + 256 + t] = a[1][r] + ebih1;
        eg[r * 768 + 512 + t] = a[2][r] + ebih2;
      }
    }

    // ---- node classifiers + sampling (wave w = row w) ----
    {
      const int w = t >> 6, lane = t & 63, b = b0 + w;
      const float e0 = xb[cur][w][lane];
      const float e1 = xb[cur][w][lane + 64];
      const float e2 = xb[cur][w][lane + 128];
      const float e3 = xb[cur][w][lane + 192];
      uint32_t k0_, k1_;
      tf2x32(0u, 42u, 0u, (uint32_t)(i * 100 + 0), k0_, k1_);
      node_phase(e0, e1, e2, e3, lane, b, i, ncW0, ncb0, 40, k0_, k1_, 0, 0,
                 true, o_nf, o_nl, &nnL[w]);
      tf2x32(0u, 42u, 0u, (uint32_t)(i * 100 + 1), k0_, k1_);
      node_phase(e0, e1, e2, e3, lane, b, i, ncW1, ncb1, 6, k0_, k1_, 40, 1,
                 false, o_nf, o_nl, &nnL[w]);
      tf2x32(0u, 42u, 0u, (uint32_t)(i * 100 + 2), k0_, k1_);
      node_phase(e0, e1, e2, e3, lane, b, i, ncW2, ncb2, 5, k0_, k1_, 46, 2,
                 false, o_nf, o_nl, &nnL[w]);
    }

    // ---- edge scan ----
    if (i >= 1) {
      const int L = i < 12 ? i : 12;
#pragma unroll
      for (int r = 0; r < NR; ++r) he[r][t] += xb[cur][r][t];
      __syncthreads();
      uint32_t ea0, ea1, eb0, eb1;
      tf2x32(0u, 42u, 0u, (uint32_t)(i * 100 + 50), ea0, ea1);
      tf2x32(0u, 42u, 0u, (uint32_t)(i * 100 + 51), eb0, eb1);
      for (int s = 0; s < L; ++s) {
        const int xs = (i - 1 - s) % 13;
        const float* eg = egi + (size_t)xs * (NR * 768);
        // prefetch combine inputs (independent of gemv)
        float ir_[NR], iz_[NR], in_[NR];
#pragma unroll
        for (int r = 0; r < NR; ++r) {
          ir_[r] = eg[r * 768 + t];
          iz_[r] = eg[r * 768 + 256 + t];
          in_[r] = eg[r * 768 + 512 + t];
        }
        float a[3][NR];
        gemv3(Ehh4, he, t, a);
        __syncthreads();                    // all he reads done
#pragma unroll
        for (int r = 0; r < NR; ++r) {
          float hr = a[0][r] + ebhh0;
          float hz = a[1][r] + ebhh1;
          float hn = a[2][r] + ebhh2;
          float ir = ir_[r], iz = iz_[r], inn = in_[r];
          float h = he[r][t];
          float rr = 1.f / (1.f + expf(-(ir + hr)));
          float zg = 1.f / (1.f + expf(-(iz + hz)));
          float n = tanhf(inn + rr * hn);
          he[r][t] = (1.f - zg) * n + zg * h;
        }
        __syncthreads();                    // he update visible
        // edge classifiers on h2 = he (scan step s -> output row L-1-s)
        {
          const int w = t >> 6, lane = t & 63, b = b0 + w;
          const int tt = L - 1 - s;
          const int ridx = tt * 512 + b;
          const size_t orow = (size_t)(base + tt) * 512 + b;
          const float e0 = he[w][lane];
          const float e1 = he[w][lane + 64];
          const float e2 = he[w][lane + 128];
          const float e3 = he[w][lane + 192];
          edge_phase(e0, e1, e2, e3, lane, ridx, orow, ecW0, ecb0, 5, ea0, ea1,
                     0, 0, o_ef, o_el);
          edge_phase(e0, e1, e2, e3, lane, ridx, orow, ecW1, ecb1, 4, eb0, eb1,
                     5, 1, o_ef, o_el);
        }
      }
      base += L;
    }
    __syncthreads();
  }

  // ---- finalize num_nodes ----
  if (t < NR) {
    float v = nnL[t];
    out[b0 + t] = (v == -1.f) ? 50.f : v;
  }
}

// ---------------- host ----------------
extern "C" void kernel_launch(void* const* d_in, const int* in_sizes, int n_in,
                              void* d_out, int out_size, void* d_ws,
                              size_t ws_size, hipStream_t stream) {
  (void)in_sizes; (void)n_in; (void)out_size; (void)ws_size;
  const float* z    = (const float*)d_in[0];
  const float* lpW  = (const float*)d_in[1];
  const float* lpb  = (const float*)d_in[2];
  const float* nWih = (const float*)d_in[3];
  const float* nWhh = (const float*)d_in[4];
  const float* nbih = (const float*)d_in[5];
  const float* nbhh = (const float*)d_in[6];
  const float* eWih = (const float*)d_in[7];
  const float* eWhh = (const float*)d_in[8];
  const float* ebih = (const float*)d_in[9];
  const float* ebhh = (const float*)d_in[10];
  const float* ncW0 = (const float*)d_in[11];
  const float* ncb0 = (const float*)d_in[12];
  const float* ncW1 = (const float*)d_in[13];
  const float* ncb1 = (const float*)d_in[14];
  const float* ncW2 = (const float*)d_in[15];
  const float* ncb2 = (const float*)d_in[16];
  const float* ecW0 = (const float*)d_in[17];
  const float* ecb0 = (const float*)d_in[18];
  const float* ecW1 = (const float*)d_in[19];
  const float* ecb1 = (const float*)d_in[20];

  setup_k<<<dim3(832), dim3(256), 0, stream>>>(nWih, nWhh, eWih, eWhh, z, lpW,
                                               lpb, (float*)d_ws);
  fused_rnn<<<dim3(NWG), dim3(NTHR), 0, stream>>>(
      nbih, nbhh, ebih, ebhh, ncW0, ncb0, ncW1, ncb1, ncW2, ncb2, ecW0, ecb0,
      ecW1, ecb1, (float*)d_ws, (float*)d_out);
}

// Round 5
// 9886.591 us; speedup vs baseline: 1.9920x; 1.7696x over previous
//
#include <hip/hip_runtime.h>
#include <stdint.h>
#include <math.h>

// ---------------------------------------------------------------------------
// Batch-parallel fused graph-generator RNN (B=512, H=256, 50 steps, window 12)
// Round-5: L2 reserved for weights (egi+outputs nontemporal, classifier W in
// LDS), dist-4 prefetch GEMV, 8-wave WG with wave specialization: waves 0-3
// run the serial GEMV recurrence, waves 4-7 run classifiers (deferred one
// scan step) + edge-gate GEMV concurrently. Per-output arithmetic VERBATIM
// from the passing round-1/3/4 kernels => same numerics.
// ---------------------------------------------------------------------------

#define NR 4
#define NWG 128
#define NTHR 512
#define KGP 68                 // 64 kg rows + 4 pad (dist-4 prefetch overrun)
#define MATS 52224u            // KGP*768 float4s per matrix
#define MATF 208896u           // floats per matrix

// ws layout (floats)
#define WS_W4   0u             // 4 * 208896 = 835584
#define WS_H0   835584u        // 131072
#define WS_EGI  966656u        // 128 * 13 * 3072 = 5111808
// total 6078464 floats = 24.3 MB

// output layout (floats)
#define O_NF 512u              // node feats [512][50][51]
#define O_EF 1306112u          // edge feats [522][512][9]
#define O_NL 3711488u          // node logprobs [512][50][3]
#define O_EL 3788288u          // edge logprobs [522][512][2]

typedef float v4f __attribute__((ext_vector_type(4)));

static __device__ __forceinline__ v4f ntload4(const float* p) {
  return __builtin_nontemporal_load((const v4f*)p);
}
static __device__ __forceinline__ void ntstore4(float* p, float a, float b,
                                                float c, float d) {
  v4f v = {a, b, c, d};
  __builtin_nontemporal_store(v, (v4f*)p);
}

// ---------------- threefry2x32 (exact JAX semantics) ----------------
__host__ __device__ inline void tf2x32(uint32_t k0, uint32_t k1,
                                       uint32_t x0, uint32_t x1,
                                       uint32_t& o0, uint32_t& o1) {
  uint32_t ks2 = k0 ^ k1 ^ 0x1BD11BDAu;
#define TFR(r) { x0 += x1; x1 = (x1 << r) | (x1 >> (32 - r)); x1 ^= x0; }
  x0 += k0; x1 += k1;
  TFR(13) TFR(15) TFR(26) TFR(6)
  x0 += k1; x1 += ks2 + 1u;
  TFR(17) TFR(29) TFR(16) TFR(24)
  x0 += ks2; x1 += k0 + 2u;
  TFR(13) TFR(15) TFR(26) TFR(6)
  x0 += k0; x1 += k1 + 3u;
  TFR(17) TFR(29) TFR(16) TFR(24)
  x0 += k1; x1 += ks2 + 4u;
  TFR(13) TFR(15) TFR(26) TFR(6)
  x0 += ks2; x1 += k0 + 5u;
#undef TFR
  o0 = x0; o1 = x1;
}

__device__ inline float gumbel_at(uint32_t k0, uint32_t k1, uint32_t idx) {
  uint32_t o0, o1;
  tf2x32(k0, k1, 0u, idx, o0, o1);
  uint32_t bits = o0 ^ o1;
  float u = __uint_as_float((bits >> 9) | 0x3f800000u) - 1.0f;
  u = fmaxf(u, 1.1754943508222875e-38f);
  return -logf(-logf(u));
}

__device__ __forceinline__ int ebase(int i) {
  return (i <= 12) ? i * (i - 1) / 2 : 78 + (i - 13) * 12;
}

// ---------------- setup kernel: W transpose + latproj ----------------
__global__ __launch_bounds__(256)
void setup_k(const float* __restrict__ nWih, const float* __restrict__ nWhh,
             const float* __restrict__ eWih, const float* __restrict__ eWhh,
             const float* __restrict__ z, const float* __restrict__ lpW,
             const float* __restrict__ lpb, float* __restrict__ ws) {
  const int wg = blockIdx.x, t = threadIdx.x;
  if (wg < 768) {
    int gid = wg * 256 + t;                 // 0..196607
    int mat = gid / 49152;
    int rem = gid - mat * 49152;
    int kg = rem / 768;
    int o = rem - kg * 768;
    const float* src = (mat == 0) ? nWih : (mat == 1) ? nWhh
                       : (mat == 2) ? eWih : eWhh;
    float4 v = *(const float4*)(src + (size_t)o * 256 + kg * 4);
    ((float4*)(ws + WS_W4))[(size_t)mat * MATS + (size_t)kg * 768 + o] = v;
  } else {
    float* h0 = ws + WS_H0;
    int idx = (wg - 768) * 256 + t;         // 0..16383
    const float alpha = 1.6732632423543772f, scale = 1.0507009873554805f;
    for (int q = 0; q < 8; ++q) {
      int flat = idx + q * 16384;           // 0..131071
      int m = flat >> 8, j = flat & 255;
      const float* zr = z + (size_t)m * 128;
      const float* wr = lpW + (size_t)j * 128;
      float s = 0.f;
      for (int k = 0; k < 128; ++k) s += zr[k] * wr[k];
      s += lpb[j];
      h0[(size_t)m * 256 + j] = scale * (s > 0.f ? s : alpha * expm1f(s));
    }
  }
}

// ---------------- coalesced 3-gate GEMV, dist-4 pipeline ----------------
// a[g][r] = sum_k W[g*256+t][k] * x[r][k]; verbatim float4 dot order.
__device__ __forceinline__ void gemv3(const float4* __restrict__ Wq,
                                      const float (*__restrict__ x)[256],
                                      int t, float a[3][NR]) {
#pragma unroll
  for (int g = 0; g < 3; ++g)
#pragma unroll
    for (int r = 0; r < NR; ++r) a[g][r] = 0.f;
  float4 w0[4], w1[4], w2[4];
#pragma unroll
  for (int p = 0; p < 4; ++p) {
    const float4* bp = Wq + (size_t)p * 768;
    w0[p] = bp[t]; w1[p] = bp[256 + t]; w2[p] = bp[512 + t];
  }
  for (int kg = 0; kg < 64; kg += 4) {
#define G3BODY(p)                                                            \
    {                                                                        \
      float4 c0 = w0[p], c1 = w1[p], c2 = w2[p];                             \
      const float4* nx = Wq + (size_t)(kg + (p) + 4) * 768;                  \
      w0[p] = nx[t]; w1[p] = nx[256 + t]; w2[p] = nx[512 + t];               \
      _Pragma("unroll")                                                      \
      for (int r = 0; r < NR; ++r) {                                         \
        const float4 xv = *(const float4*)&x[r][(kg + (p)) * 4];             \
        a[0][r] += xv.x * c0.x + xv.y * c0.y + xv.z * c0.z + xv.w * c0.w;    \
        a[1][r] += xv.x * c1.x + xv.y * c1.y + xv.z * c1.z + xv.w * c1.w;    \
        a[2][r] += xv.x * c2.x + xv.y * c2.y + xv.z * c2.z + xv.w * c2.w;    \
      }                                                                      \
    }
    G3BODY(0) G3BODY(1) G3BODY(2) G3BODY(3)
#undef G3BODY
  }
}

// ---------------- fused dual 3-gate GEMV, dist-2 pipeline ----------------
__device__ __forceinline__ void gemv6(const float4* __restrict__ Wa,
                                      const float4* __restrict__ Wb,
                                      const float (*__restrict__ xa)[256],
                                      const float (*__restrict__ xh)[256],
                                      int t, float ga[3][NR], float gb[3][NR]) {
#pragma unroll
  for (int g = 0; g < 3; ++g)
#pragma unroll
    for (int r = 0; r < NR; ++r) { ga[g][r] = 0.f; gb[g][r] = 0.f; }
  float4 wa0[2], wa1[2], wa2[2], wb0[2], wb1[2], wb2[2];
#pragma unroll
  for (int p = 0; p < 2; ++p) {
    const float4* ba = Wa + (size_t)p * 768;
    const float4* bb = Wb + (size_t)p * 768;
    wa0[p] = ba[t]; wa1[p] = ba[256 + t]; wa2[p] = ba[512 + t];
    wb0[p] = bb[t]; wb1[p] = bb[256 + t]; wb2[p] = bb[512 + t];
  }
  for (int kg = 0; kg < 64; kg += 2) {
#define G6BODY(p)                                                            \
    {                                                                        \
      float4 cA0 = wa0[p], cA1 = wa1[p], cA2 = wa2[p];                       \
      float4 cB0 = wb0[p], cB1 = wb1[p], cB2 = wb2[p];                       \
      const float4* na = Wa + (size_t)(kg + (p) + 2) * 768;                  \
      const float4* nb = Wb + (size_t)(kg + (p) + 2) * 768;                  \
      wa0[p] = na[t]; wa1[p] = na[256 + t]; wa2[p] = na[512 + t];            \
      wb0[p] = nb[t]; wb1[p] = nb[256 + t]; wb2[p] = nb[512 + t];            \
      _Pragma("unroll")                                                      \
      for (int r = 0; r < NR; ++r) {                                         \
        const float4 xv = *(const float4*)&xa[r][(kg + (p)) * 4];            \
        const float4 hv = *(const float4*)&xh[r][(kg + (p)) * 4];            \
        ga[0][r] += xv.x * cA0.x + xv.y * cA0.y + xv.z * cA0.z + xv.w * cA0.w;\
        ga[1][r] += xv.x * cA1.x + xv.y * cA1.y + xv.z * cA1.z + xv.w * cA1.w;\
        ga[2][r] += xv.x * cA2.x + xv.y * cA2.y + xv.z * cA2.z + xv.w * cA2.w;\
        gb[0][r] += hv.x * cB0.x + hv.y * cB0.y + hv.z * cB0.z + hv.w * cB0.w;\
        gb[1][r] += hv.x * cB1.x + hv.y * cB1.y + hv.z * cB1.z + hv.w * cB1.w;\
        gb[2][r] += hv.x * cB2.x + hv.y * cB2.y + hv.z * cB2.z + hv.w * cB2.w;\
      }                                                                      \
    }
    G6BODY(0) G6BODY(1)
#undef G6BODY
  }
}

// ---------------- node classifier phase (verbatim math, nt stores) ---------
__device__ __forceinline__ void node_phase(
    float e0, float e1, float e2, float e3, int lane, int b, int step,
    const float* W, const float* bb, int nf, uint32_t kk0, uint32_t kk1,
    int coff, int jidx, bool do_arg, float* o_nf, float* o_nl, float* nnrow) {
  float ml = 0.f;
  for (int jf = 0; jf < nf; ++jf) {
    const float* wr = W + (size_t)jf * 256;
    float p = e0 * wr[lane] + e1 * wr[lane + 64] + e2 * wr[lane + 128] +
              e3 * wr[lane + 192];
#pragma unroll
    for (int d = 32; d; d >>= 1) p += __shfl_xor(p, d);
    if (lane == jf) ml = p + bb[jf];
  }
  const bool act = lane < nf;
  float g = act ? gumbel_at(kk0, kk1, (uint32_t)(b * nf + lane)) : 0.f;
  float tv = act ? (ml + g) / 1e-3f : -INFINITY;
  float mx = tv;
#pragma unroll
  for (int d = 32; d; d >>= 1) mx = fmaxf(mx, __shfl_xor(mx, d));
  float e = act ? expf(tv - mx) : 0.f;
  float se = e;
#pragma unroll
  for (int d = 32; d; d >>= 1) se += __shfl_xor(se, d);
  float s = act ? e / se : 0.f;
  float mx2 = act ? ml : -INFINITY;
#pragma unroll
  for (int d = 32; d; d >>= 1) mx2 = fmaxf(mx2, __shfl_xor(mx2, d));
  float e2v = act ? expf(ml - mx2) : 0.f;
  float se2 = e2v;
#pragma unroll
  for (int d = 32; d; d >>= 1) se2 += __shfl_xor(se2, d);
  float logp = ml - mx2 - logf(se2);
  float w = act ? s * logp : 0.f;
#pragma unroll
  for (int d = 32; d; d >>= 1) w += __shfl_xor(w, d);
  if (act)
    __builtin_nontemporal_store(s,
        &o_nf[((size_t)b * 50 + step) * 51 + coff + lane]);
  if (lane == 0)
    __builtin_nontemporal_store(w, &o_nl[((size_t)b * 50 + step) * 3 + jidx]);
  if (do_arg) {
    float av = act ? s : -1.f;
    int ai = lane;
#pragma unroll
    for (int d = 32; d; d >>= 1) {
      float ov = __shfl_xor(av, d);
      int oi = __shfl_xor(ai, d);
      if (ov > av || (ov == av && oi < ai)) { av = ov; ai = oi; }
    }
    if (lane == 0 && ai == 39 && nnrow[0] == -1.0f)
      nnrow[0] = (float)(step + 1);
  }
}

// ---------------- edge classifier phase (verbatim math, nt stores) ---------
__device__ __forceinline__ void edge_phase(
    float e0, float e1, float e2, float e3, int lane, int ridx, size_t orow,
    const float* W, const float* bb, int nf, uint32_t kk0, uint32_t kk1,
    int coff, int jidx, float* o_ef, float* o_el) {
  float ml = 0.f;
  for (int jf = 0; jf < nf; ++jf) {
    const float* wr = W + (size_t)jf * 256;
    float p = e0 * wr[lane] + e1 * wr[lane + 64] + e2 * wr[lane + 128] +
              e3 * wr[lane + 192];
#pragma unroll
    for (int d = 32; d; d >>= 1) p += __shfl_xor(p, d);
    if (lane == jf) ml = p + bb[jf];
  }
  const bool act = lane < nf;
  float g = act ? gumbel_at(kk0, kk1, (uint32_t)(ridx * nf + lane)) : 0.f;
  float tv = act ? (ml + g) / 1e-3f : -INFINITY;
  float mx = tv;
#pragma unroll
  for (int d = 32; d; d >>= 1) mx = fmaxf(mx, __shfl_xor(mx, d));
  float e = act ? expf(tv - mx) : 0.f;
  float se = e;
#pragma unroll
  for (int d = 32; d; d >>= 1) se += __shfl_xor(se, d);
  float s = act ? e / se : 0.f;
  // NOTE: edge path takes log_softmax of the SAMPLES (faithful to source)
  float mx2 = act ? s : -INFINITY;
#pragma unroll
  for (int d = 32; d; d >>= 1) mx2 = fmaxf(mx2, __shfl_xor(mx2, d));
  float e2v = act ? expf(s - mx2) : 0.f;
  float se2 = e2v;
#pragma unroll
  for (int d = 32; d; d >>= 1) se2 += __shfl_xor(se2, d);
  float logp = s - mx2 - logf(se2);
  float w = act ? s * logp : 0.f;
#pragma unroll
  for (int d = 32; d; d >>= 1) w += __shfl_xor(w, d);
  if (act) __builtin_nontemporal_store(s, &o_ef[orow * 9 + coff + lane]);
  if (lane == 0) __builtin_nontemporal_store(w, &o_el[orow * 2 + jidx]);
}

// ---------------- grouped classifier helpers ----------------
__device__ __forceinline__ void node_cls_all(
    const float (*emb)[256], int tc, int b0, int step, const float* cW,
    const float* cB, float* o_nf, float* o_nl, float* nnL) {
  const int w = tc >> 6, lane = tc & 63, b = b0 + w;
  const float e0 = emb[w][lane];
  const float e1 = emb[w][lane + 64];
  const float e2 = emb[w][lane + 128];
  const float e3 = emb[w][lane + 192];
  uint32_t k0_, k1_;
  tf2x32(0u, 42u, 0u, (uint32_t)(step * 100 + 0), k0_, k1_);
  node_phase(e0, e1, e2, e3, lane, b, step, cW, cB, 40, k0_, k1_, 0, 0, true,
             o_nf, o_nl, &nnL[w]);
  tf2x32(0u, 42u, 0u, (uint32_t)(step * 100 + 1), k0_, k1_);
  node_phase(e0, e1, e2, e3, lane, b, step, cW + 40 * 256, cB + 40, 6, k0_,
             k1_, 40, 1, false, o_nf, o_nl, &nnL[w]);
  tf2x32(0u, 42u, 0u, (uint32_t)(step * 100 + 2), k0_, k1_);
  node_phase(e0, e1, e2, e3, lane, b, step, cW + 46 * 256, cB + 46, 5, k0_,
             k1_, 46, 2, false, o_nf, o_nl, &nnL[w]);
}

__device__ __forceinline__ void edge_cls_step(
    int i, int s, const float (*h2)[256], int tc, int b0, const float* cW,
    const float* cB, float* o_ef, float* o_el) {
  const int L = (i < 12) ? i : 12;
  const int tt = L - 1 - s;
  const int w = tc >> 6, lane = tc & 63, b = b0 + w;
  const int ridx = tt * 512 + b;
  const size_t orow = (size_t)(ebase(i) + tt) * 512 + b;
  uint32_t ea0, ea1, eb0, eb1;
  tf2x32(0u, 42u, 0u, (uint32_t)(i * 100 + 50), ea0, ea1);
  tf2x32(0u, 42u, 0u, (uint32_t)(i * 100 + 51), eb0, eb1);
  const float e0 = h2[w][lane];
  const float e1 = h2[w][lane + 64];
  const float e2 = h2[w][lane + 128];
  const float e3 = h2[w][lane + 192];
  edge_phase(e0, e1, e2, e3, lane, ridx, orow, cW + 51 * 256, cB + 51, 5, ea0,
             ea1, 0, 0, o_ef, o_el);
  edge_phase(e0, e1, e2, e3, lane, ridx, orow, cW + 56 * 256, cB + 56, 4, eb0,
             eb1, 5, 1, o_ef, o_el);
}

__device__ __forceinline__ void do_eih(const float4* __restrict__ Eih4,
                                       const float (*__restrict__ x)[256],
                                       int tc, float* __restrict__ egi,
                                       int slot, float eb0, float eb1,
                                       float eb2) {
  float a[3][NR];
  gemv3(Eih4, x, tc, a);
  float* eg = egi + (size_t)slot * 3072 + tc * 12;
  ntstore4(eg, a[0][0] + eb0, a[1][0] + eb1, a[2][0] + eb2, a[0][1] + eb0);
  ntstore4(eg + 4, a[1][1] + eb1, a[2][1] + eb2, a[0][2] + eb0,
           a[1][2] + eb1);
  ntstore4(eg + 8, a[2][2] + eb2, a[0][3] + eb0, a[1][3] + eb1,
           a[2][3] + eb2);
}

// ---------------- the fused kernel ----------------
__global__ __launch_bounds__(NTHR, 2)
void fused_rnn(const float* __restrict__ nbih, const float* __restrict__ nbhh,
               const float* __restrict__ ebih, const float* __restrict__ ebhh,
               const float* __restrict__ ncW0, const float* __restrict__ ncb0,
               const float* __restrict__ ncW1, const float* __restrict__ ncb1,
               const float* __restrict__ ncW2, const float* __restrict__ ncb2,
               const float* __restrict__ ecW0, const float* __restrict__ ecb0,
               const float* __restrict__ ecW1, const float* __restrict__ ecb1,
               float* __restrict__ ws, float* __restrict__ out) {
  __shared__ float xb[2][NR][256];   // node_emb ping-pong
  __shared__ float ht[NR][256];      // node hidden input
  __shared__ float hs[2][NR][256];   // edge_h ping-pong
  __shared__ float clsW[60][256];    // classifier weights
  __shared__ float clsB[64];         // classifier biases
  __shared__ float nnL[NR];

  const int t = threadIdx.x;
  const int wg = blockIdx.x;
  const int b0 = wg * NR;
  const bool isg = t < 256;          // waves 0-3: GEMV; waves 4-7: classifiers
  const int tc = t & 255;

  const float4* W4q = (const float4*)(ws + WS_W4);
  const float4* Wih4 = W4q;
  const float4* Whh4 = W4q + MATS;
  const float4* Eih4 = W4q + 2 * MATS;
  const float4* Ehh4 = W4q + 3 * MATS;
  const float* h0 = ws + WS_H0;
  float* egi = ws + WS_EGI + (size_t)wg * 39936u;   // 13 slots * 3072

  float* o_nf = out + O_NF;
  float* o_ef = out + O_EF;
  float* o_nl = out + O_NL;
  float* o_el = out + O_EL;

  // ---- stage classifier weights/biases into LDS ----
  for (int x = t; x < 40 * 256; x += NTHR) (&clsW[0][0])[x] = ncW0[x];
  for (int x = t; x < 6 * 256; x += NTHR) (&clsW[40][0])[x] = ncW1[x];
  for (int x = t; x < 5 * 256; x += NTHR) (&clsW[46][0])[x] = ncW2[x];
  for (int x = t; x < 5 * 256; x += NTHR) (&clsW[51][0])[x] = ecW0[x];
  for (int x = t; x < 4 * 256; x += NTHR) (&clsW[56][0])[x] = ecW1[x];
  if (t < 40) clsB[t] = ncb0[t];
  else if (t < 46) clsB[t] = ncb1[t - 40];
  else if (t < 51) clsB[t] = ncb2[t - 46];
  else if (t < 56) clsB[t] = ecb0[t - 51];
  else if (t < 60) clsB[t] = ecb1[t - 56];

  const float nbih0 = nbih[tc], nbih1 = nbih[256 + tc], nbih2 = nbih[512 + tc];
  const float nbhh0 = nbhh[tc], nbhh1 = nbhh[256 + tc], nbhh2 = nbhh[512 + tc];
  const float ebih0 = ebih[tc], ebih1 = ebih[256 + tc], ebih2 = ebih[512 + tc];
  const float ebhh0 = ebhh[tc], ebhh1 = ebhh[256 + tc], ebhh2 = ebhh[512 + tc];

  if (isg) {
#pragma unroll
    for (int r = 0; r < NR; ++r) {
      hs[0][r][tc] = 0.f;
      ht[r][tc] = h0[(size_t)(b0 + r) * 256 + tc];
    }
  }
  if (t < NR) nnL[t] = -1.f;
  __syncthreads();

  int hp = 0;                        // hs[hp] holds current valid edge_h
  for (int i = 0; i < 50; ++i) {
    const int cur = i & 1, prv = cur ^ 1;
    const int L = (i < 12) ? i : 12;

    // ---- Phase A: build ht (gemv waves) ----
    if (i >= 1) {
      if (isg) {
#pragma unroll
        for (int r = 0; r < NR; ++r) {
          float v = xb[prv][r][tc];
          if (i >= 2) v += hs[hp][r][tc];
          ht[r][tc] = v;
        }
      }
      __syncthreads();
    }

    // ---- Phase B: node GRU (gemv) || deferred edge-cls(i-1, last) (cls) ----
    if (isg) {
      float gi[3][NR], gh[3][NR];
      if (i >= 1) {
        gemv6(Wih4, Whh4, xb[prv], ht, tc, gi, gh);
      } else {
        gemv3(Whh4, ht, tc, gh);
#pragma unroll
        for (int g = 0; g < 3; ++g)
#pragma unroll
          for (int r = 0; r < NR; ++r) gi[g][r] = 0.f;
      }
#pragma unroll
      for (int r = 0; r < NR; ++r) {
        float ir  = gi[0][r] + nbih0;
        float iz  = gi[1][r] + nbih1;
        float inn = gi[2][r] + nbih2;
        float hr = gh[0][r] + nbhh0;
        float hz = gh[1][r] + nbhh1;
        float hn = gh[2][r] + nbhh2;
        float h = ht[r][tc];
        float rr = 1.f / (1.f + expf(-(ir + hr)));
        float zg = 1.f / (1.f + expf(-(iz + hz)));
        float n = tanhf(inn + rr * hn);
        float hv = (1.f - zg) * n + zg * h;
        xb[cur][r][tc] = hv;
        if (i >= 1) hs[hp ^ 1][r][tc] = hs[hp][r][tc] + hv;  // edge_h += node_h
      }
    } else if (i >= 2) {
      const int Lp = ((i - 1) < 12) ? (i - 1) : 12;
      edge_cls_step(i - 1, Lp - 1, hs[hp], tc, b0, &clsW[0][0], clsB, o_ef,
                    o_el);
    }
    __syncthreads();
    if (i >= 1) hp ^= 1;

    // ---- Phase C: edge scan (gemv) || classifiers + eih (cls) ----
    if (i == 0) {
      if (isg) do_eih(Eih4, xb[cur], tc, egi, 0, ebih0, ebih1, ebih2);
      else node_cls_all(xb[cur], tc, b0, 0, &clsW[0][0], clsB, o_nf, o_nl,
                        nnL);
      __syncthreads();
    } else {
      const int sE = (L >= 2) ? 1 : 0;
      for (int s = 0; s < L; ++s) {
        if (isg) {
          const float* eg = egi + (size_t)((i - 1 - s) % 13) * 3072 + tc * 12;
          v4f f0 = ntload4(eg);
          v4f f1 = ntload4(eg + 4);
          v4f f2 = ntload4(eg + 8);
          float a[3][NR];
          gemv3(Ehh4, hs[hp], tc, a);
          float ir_[NR] = {f0.x, f0.w, f1.z, f2.y};
          float iz_[NR] = {f0.y, f1.x, f1.w, f2.z};
          float in_[NR] = {f0.z, f1.y, f2.x, f2.w};
#pragma unroll
          for (int r = 0; r < NR; ++r) {
            float hr = a[0][r] + ebhh0;
            float hz = a[1][r] + ebhh1;
            float hn = a[2][r] + ebhh2;
            float h = hs[hp][r][tc];
            float rr = 1.f / (1.f + expf(-(ir_[r] + hr)));
            float zg = 1.f / (1.f + expf(-(iz_[r] + hz)));
            float n = tanhf(in_[r] + rr * hn);
            hs[hp ^ 1][r][tc] = (1.f - zg) * n + zg * h;
          }
        } else {
          if (s == 0)
            node_cls_all(xb[cur], tc, b0, i, &clsW[0][0], clsB, o_nf, o_nl,
                         nnL);
          if (s == sE && i <= 48)
            do_eih(Eih4, xb[cur], tc, egi, i % 13, ebih0, ebih1, ebih2);
          if (s >= 1)
            edge_cls_step(i, s - 1, hs[hp], tc, b0, &clsW[0][0], clsB, o_ef,
                          o_el);
        }
        __syncthreads();
        hp ^= 1;
      }
    }
  }

  // ---- final: last edge classifier + num_nodes ----
  if (!isg)
    edge_cls_step(49, 11, hs[hp], tc, b0, &clsW[0][0], clsB, o_ef, o_el);
  if (t < NR) {
    float v = nnL[t];
    __builtin_nontemporal_store((v == -1.f) ? 50.f : v, &out[b0 + t]);
  }
}

// ---------------- host ----------------
extern "C" void kernel_launch(void* const* d_in, const int* in_sizes, int n_in,
                              void* d_out, int out_size, void* d_ws,
                              size_t ws_size, hipStream_t stream) {
  (void)in_sizes; (void)n_in; (void)out_size; (void)ws_size;
  const float* z    = (const float*)d_in[0];
  const float* lpW  = (const float*)d_in[1];
  const float* lpb  = (const float*)d_in[2];
  const float* nWih = (const float*)d_in[3];
  const float* nWhh = (const float*)d_in[4];
  const float* nbih = (const float*)d_in[5];
  const float* nbhh = (const float*)d_in[6];
  const float* eWih = (const float*)d_in[7];
  const float* eWhh = (const float*)d_in[8];
  const float* ebih = (const float*)d_in[9];
  const float* ebhh = (const float*)d_in[10];
  const float* ncW0 = (const float*)d_in[11];
  const float* ncb0 = (const float*)d_in[12];
  const float* ncW1 = (const float*)d_in[13];
  const float* ncb1 = (const float*)d_in[14];
  const float* ncW2 = (const float*)d_in[15];
  const float* ncb2 = (const float*)d_in[16];
  const float* ecW0 = (const float*)d_in[17];
  const float* ecb0 = (const float*)d_in[18];
  const float* ecW1 = (const float*)d_in[19];
  const float* ecb1 = (const float*)d_in[20];

  setup_k<<<dim3(832), dim3(256), 0, stream>>>(nWih, nWhh, eWih, eWhh, z, lpW,
                                               lpb, (float*)d_ws);
  fused_rnn<<<dim3(NWG), dim3(NTHR), 0, stream>>>(
      nbih, nbhh, ebih, ebhh, ncW0, ncb0, ncW1, ncb1, ncW2, ncb2, ecW0, ecb0,
      ecW1, ecb1, (float*)d_ws, (float*)d_out);
}

// Round 6
// 9772.441 us; speedup vs baseline: 2.0152x; 1.0117x over previous
//
#include <hip/hip_runtime.h>
#include <stdint.h>
#include <math.h>

// ---------------------------------------------------------------------------
// Batch-parallel fused graph-generator RNN (B=512, H=256, 50 steps, window 12)
// Round-6: egi ring back to CACHED loads/stores (round-5 NT bypass forced
// 800MB of HBM traffic = the latency wall). W stream L2-resident; dist-8
// prefetch GEMV covers L3 latency. NT stores only for final outputs.
// Per-output arithmetic VERBATIM from passing rounds => same numerics.
// ---------------------------------------------------------------------------

#define NR 4
#define NWG 128
#define NTHR 512
#define KGP 72                 // 64 kg rows + 8 pad (dist-8 prefetch overrun)
#define MATS 55296u            // KGP*768 float4s per matrix
#define MATF 221184u           // floats per matrix

// ws layout (floats)
#define WS_W4   0u             // 4 * 221184 = 884736
#define WS_H0   884736u        // 131072
#define WS_EGI  1015808u       // 128 * 13 * 3072 = 5111808
// total 6127616 floats = 24.5 MB

// output layout (floats)
#define O_NF 512u              // node feats [512][50][51]
#define O_EF 1306112u          // edge feats [522][512][9]
#define O_NL 3711488u          // node logprobs [512][50][3]
#define O_EL 3788288u          // edge logprobs [522][512][2]

typedef float v4f __attribute__((ext_vector_type(4)));

// ---------------- threefry2x32 (exact JAX semantics) ----------------
__host__ __device__ inline void tf2x32(uint32_t k0, uint32_t k1,
                                       uint32_t x0, uint32_t x1,
                                       uint32_t& o0, uint32_t& o1) {
  uint32_t ks2 = k0 ^ k1 ^ 0x1BD11BDAu;
#define TFR(r) { x0 += x1; x1 = (x1 << r) | (x1 >> (32 - r)); x1 ^= x0; }
  x0 += k0; x1 += k1;
  TFR(13) TFR(15) TFR(26) TFR(6)
  x0 += k1; x1 += ks2 + 1u;
  TFR(17) TFR(29) TFR(16) TFR(24)
  x0 += ks2; x1 += k0 + 2u;
  TFR(13) TFR(15) TFR(26) TFR(6)
  x0 += k0; x1 += k1 + 3u;
  TFR(17) TFR(29) TFR(16) TFR(24)
  x0 += k1; x1 += ks2 + 4u;
  TFR(13) TFR(15) TFR(26) TFR(6)
  x0 += ks2; x1 += k0 + 5u;
#undef TFR
  o0 = x0; o1 = x1;
}

__device__ inline float gumbel_at(uint32_t k0, uint32_t k1, uint32_t idx) {
  uint32_t o0, o1;
  tf2x32(k0, k1, 0u, idx, o0, o1);
  uint32_t bits = o0 ^ o1;
  float u = __uint_as_float((bits >> 9) | 0x3f800000u) - 1.0f;
  u = fmaxf(u, 1.1754943508222875e-38f);
  return -logf(-logf(u));
}

__device__ __forceinline__ int ebase(int i) {
  return (i <= 12) ? i * (i - 1) / 2 : 78 + (i - 13) * 12;
}

// ---------------- setup kernel: W transpose + latproj ----------------
__global__ __launch_bounds__(256)
void setup_k(const float* __restrict__ nWih, const float* __restrict__ nWhh,
             const float* __restrict__ eWih, const float* __restrict__ eWhh,
             const float* __restrict__ z, const float* __restrict__ lpW,
             const float* __restrict__ lpb, float* __restrict__ ws) {
  const int wg = blockIdx.x, t = threadIdx.x;
  if (wg < 768) {
    int gid = wg * 256 + t;                 // 0..196607
    int mat = gid / 49152;
    int rem = gid - mat * 49152;
    int kg = rem / 768;
    int o = rem - kg * 768;
    const float* src = (mat == 0) ? nWih : (mat == 1) ? nWhh
                       : (mat == 2) ? eWih : eWhh;
    float4 v = *(const float4*)(src + (size_t)o * 256 + kg * 4);
    ((float4*)(ws + WS_W4))[(size_t)mat * MATS + (size_t)kg * 768 + o] = v;
  } else {
    float* h0 = ws + WS_H0;
    int idx = (wg - 768) * 256 + t;         // 0..16383
    const float alpha = 1.6732632423543772f, scale = 1.0507009873554805f;
    for (int q = 0; q < 8; ++q) {
      int flat = idx + q * 16384;           // 0..131071
      int m = flat >> 8, j = flat & 255;
      const float* zr = z + (size_t)m * 128;
      const float* wr = lpW + (size_t)j * 128;
      float s = 0.f;
      for (int k = 0; k < 128; ++k) s += zr[k] * wr[k];
      s += lpb[j];
      h0[(size_t)m * 256 + j] = scale * (s > 0.f ? s : alpha * expm1f(s));
    }
  }
}

// ---------------- coalesced 3-gate GEMV, dist-8 pipeline ----------------
// a[g][r] = sum_k W[g*256+t][k] * x[r][k]; verbatim float4 dot order.
__device__ __forceinline__ void gemv3(const float4* __restrict__ Wq,
                                      const float (*__restrict__ x)[256],
                                      int t, float a[3][NR]) {
#pragma unroll
  for (int g = 0; g < 3; ++g)
#pragma unroll
    for (int r = 0; r < NR; ++r) a[g][r] = 0.f;
  float4 w0[8], w1[8], w2[8];
#pragma unroll
  for (int p = 0; p < 8; ++p) {
    const float4* bp = Wq + (size_t)p * 768;
    w0[p] = bp[t]; w1[p] = bp[256 + t]; w2[p] = bp[512 + t];
  }
  for (int kg = 0; kg < 64; kg += 8) {
#define G3BODY(p)                                                            \
    {                                                                        \
      float4 c0 = w0[p], c1 = w1[p], c2 = w2[p];                             \
      const float4* nx = Wq + (size_t)(kg + (p) + 8) * 768;                  \
      w0[p] = nx[t]; w1[p] = nx[256 + t]; w2[p] = nx[512 + t];               \
      _Pragma("unroll")                                                      \
      for (int r = 0; r < NR; ++r) {                                         \
        const float4 xv = *(const float4*)&x[r][(kg + (p)) * 4];             \
        a[0][r] += xv.x * c0.x + xv.y * c0.y + xv.z * c0.z + xv.w * c0.w;    \
        a[1][r] += xv.x * c1.x + xv.y * c1.y + xv.z * c1.z + xv.w * c1.w;    \
        a[2][r] += xv.x * c2.x + xv.y * c2.y + xv.z * c2.z + xv.w * c2.w;    \
      }                                                                      \
    }
    G3BODY(0) G3BODY(1) G3BODY(2) G3BODY(3)
    G3BODY(4) G3BODY(5) G3BODY(6) G3BODY(7)
#undef G3BODY
  }
}

// ---------------- fused dual 3-gate GEMV, dist-2 pipeline ----------------
__device__ __forceinline__ void gemv6(const float4* __restrict__ Wa,
                                      const float4* __restrict__ Wb,
                                      const float (*__restrict__ xa)[256],
                                      const float (*__restrict__ xh)[256],
                                      int t, float ga[3][NR], float gb[3][NR]) {
#pragma unroll
  for (int g = 0; g < 3; ++g)
#pragma unroll
    for (int r = 0; r < NR; ++r) { ga[g][r] = 0.f; gb[g][r] = 0.f; }
  float4 wa0[2], wa1[2], wa2[2], wb0[2], wb1[2], wb2[2];
#pragma unroll
  for (int p = 0; p < 2; ++p) {
    const float4* ba = Wa + (size_t)p * 768;
    const float4* bb = Wb + (size_t)p * 768;
    wa0[p] = ba[t]; wa1[p] = ba[256 + t]; wa2[p] = ba[512 + t];
    wb0[p] = bb[t]; wb1[p] = bb[256 + t]; wb2[p] = bb[512 + t];
  }
  for (int kg = 0; kg < 64; kg += 2) {
#define G6BODY(p)                                                            \
    {                                                                        \
      float4 cA0 = wa0[p], cA1 = wa1[p], cA2 = wa2[p];                       \
      float4 cB0 = wb0[p], cB1 = wb1[p], cB2 = wb2[p];                       \
      const float4* na = Wa + (size_t)(kg + (p) + 2) * 768;                  \
      const float4* nb = Wb + (size_t)(kg + (p) + 2) * 768;                  \
      wa0[p] = na[t]; wa1[p] = na[256 + t]; wa2[p] = na[512 + t];            \
      wb0[p] = nb[t]; wb1[p] = nb[256 + t]; wb2[p] = nb[512 + t];            \
      _Pragma("unroll")                                                      \
      for (int r = 0; r < NR; ++r) {                                         \
        const float4 xv = *(const float4*)&xa[r][(kg + (p)) * 4];            \
        const float4 hv = *(const float4*)&xh[r][(kg + (p)) * 4];            \
        ga[0][r] += xv.x * cA0.x + xv.y * cA0.y + xv.z * cA0.z + xv.w * cA0.w;\
        ga[1][r] += xv.x * cA1.x + xv.y * cA1.y + xv.z * cA1.z + xv.w * cA1.w;\
        ga[2][r] += xv.x * cA2.x + xv.y * cA2.y + xv.z * cA2.z + xv.w * cA2.w;\
        gb[0][r] += hv.x * cB0.x + hv.y * cB0.y + hv.z * cB0.z + hv.w * cB0.w;\
        gb[1][r] += hv.x * cB1.x + hv.y * cB1.y + hv.z * cB1.z + hv.w * cB1.w;\
        gb[2][r] += hv.x * cB2.x + hv.y * cB2.y + hv.z * cB2.z + hv.w * cB2.w;\
      }                                                                      \
    }
    G6BODY(0) G6BODY(1)
#undef G6BODY
  }
}

// ---------------- node classifier phase (verbatim math, nt stores) ---------
__device__ __forceinline__ void node_phase(
    float e0, float e1, float e2, float e3, int lane, int b, int step,
    const float* W, const float* bb, int nf, uint32_t kk0, uint32_t kk1,
    int coff, int jidx, bool do_arg, float* o_nf, float* o_nl, float* nnrow) {
  float ml = 0.f;
  for (int jf = 0; jf < nf; ++jf) {
    const float* wr = W + (size_t)jf * 256;
    float p = e0 * wr[lane] + e1 * wr[lane + 64] + e2 * wr[lane + 128] +
              e3 * wr[lane + 192];
#pragma unroll
    for (int d = 32; d; d >>= 1) p += __shfl_xor(p, d);
    if (lane == jf) ml = p + bb[jf];
  }
  const bool act = lane < nf;
  float g = act ? gumbel_at(kk0, kk1, (uint32_t)(b * nf + lane)) : 0.f;
  float tv = act ? (ml + g) / 1e-3f : -INFINITY;
  float mx = tv;
#pragma unroll
  for (int d = 32; d; d >>= 1) mx = fmaxf(mx, __shfl_xor(mx, d));
  float e = act ? expf(tv - mx) : 0.f;
  float se = e;
#pragma unroll
  for (int d = 32; d; d >>= 1) se += __shfl_xor(se, d);
  float s = act ? e / se : 0.f;
  float mx2 = act ? ml : -INFINITY;
#pragma unroll
  for (int d = 32; d; d >>= 1) mx2 = fmaxf(mx2, __shfl_xor(mx2, d));
  float e2v = act ? expf(ml - mx2) : 0.f;
  float se2 = e2v;
#pragma unroll
  for (int d = 32; d; d >>= 1) se2 += __shfl_xor(se2, d);
  float logp = ml - mx2 - logf(se2);
  float w = act ? s * logp : 0.f;
#pragma unroll
  for (int d = 32; d; d >>= 1) w += __shfl_xor(w, d);
  if (act)
    __builtin_nontemporal_store(s,
        &o_nf[((size_t)b * 50 + step) * 51 + coff + lane]);
  if (lane == 0)
    __builtin_nontemporal_store(w, &o_nl[((size_t)b * 50 + step) * 3 + jidx]);
  if (do_arg) {
    float av = act ? s : -1.f;
    int ai = lane;
#pragma unroll
    for (int d = 32; d; d >>= 1) {
      float ov = __shfl_xor(av, d);
      int oi = __shfl_xor(ai, d);
      if (ov > av || (ov == av && oi < ai)) { av = ov; ai = oi; }
    }
    if (lane == 0 && ai == 39 && nnrow[0] == -1.0f)
      nnrow[0] = (float)(step + 1);
  }
}

// ---------------- edge classifier phase (verbatim math, nt stores) ---------
__device__ __forceinline__ void edge_phase(
    float e0, float e1, float e2, float e3, int lane, int ridx, size_t orow,
    const float* W, const float* bb, int nf, uint32_t kk0, uint32_t kk1,
    int coff, int jidx, float* o_ef, float* o_el) {
  float ml = 0.f;
  for (int jf = 0; jf < nf; ++jf) {
    const float* wr = W + (size_t)jf * 256;
    float p = e0 * wr[lane] + e1 * wr[lane + 64] + e2 * wr[lane + 128] +
              e3 * wr[lane + 192];
#pragma unroll
    for (int d = 32; d; d >>= 1) p += __shfl_xor(p, d);
    if (lane == jf) ml = p + bb[jf];
  }
  const bool act = lane < nf;
  float g = act ? gumbel_at(kk0, kk1, (uint32_t)(ridx * nf + lane)) : 0.f;
  float tv = act ? (ml + g) / 1e-3f : -INFINITY;
  float mx = tv;
#pragma unroll
  for (int d = 32; d; d >>= 1) mx = fmaxf(mx, __shfl_xor(mx, d));
  float e = act ? expf(tv - mx) : 0.f;
  float se = e;
#pragma unroll
  for (int d = 32; d; d >>= 1) se += __shfl_xor(se, d);
  float s = act ? e / se : 0.f;
  // NOTE: edge path takes log_softmax of the SAMPLES (faithful to source)
  float mx2 = act ? s : -INFINITY;
#pragma unroll
  for (int d = 32; d; d >>= 1) mx2 = fmaxf(mx2, __shfl_xor(mx2, d));
  float e2v = act ? expf(s - mx2) : 0.f;
  float se2 = e2v;
#pragma unroll
  for (int d = 32; d; d >>= 1) se2 += __shfl_xor(se2, d);
  float logp = s - mx2 - logf(se2);
  float w = act ? s * logp : 0.f;
#pragma unroll
  for (int d = 32; d; d >>= 1) w += __shfl_xor(w, d);
  if (act) __builtin_nontemporal_store(s, &o_ef[orow * 9 + coff + lane]);
  if (lane == 0) __builtin_nontemporal_store(w, &o_el[orow * 2 + jidx]);
}

// ---------------- grouped classifier helpers ----------------
__device__ __forceinline__ void node_cls_all(
    const float (*emb)[256], int tc, int b0, int step, const float* cW,
    const float* cB, float* o_nf, float* o_nl, float* nnL) {
  const int w = tc >> 6, lane = tc & 63, b = b0 + w;
  const float e0 = emb[w][lane];
  const float e1 = emb[w][lane + 64];
  const float e2 = emb[w][lane + 128];
  const float e3 = emb[w][lane + 192];
  uint32_t k0_, k1_;
  tf2x32(0u, 42u, 0u, (uint32_t)(step * 100 + 0), k0_, k1_);
  node_phase(e0, e1, e2, e3, lane, b, step, cW, cB, 40, k0_, k1_, 0, 0, true,
             o_nf, o_nl, &nnL[w]);
  tf2x32(0u, 42u, 0u, (uint32_t)(step * 100 + 1), k0_, k1_);
  node_phase(e0, e1, e2, e3, lane, b, step, cW + 40 * 256, cB + 40, 6, k0_,
             k1_, 40, 1, false, o_nf, o_nl, &nnL[w]);
  tf2x32(0u, 42u, 0u, (uint32_t)(step * 100 + 2), k0_, k1_);
  node_phase(e0, e1, e2, e3, lane, b, step, cW + 46 * 256, cB + 46, 5, k0_,
             k1_, 46, 2, false, o_nf, o_nl, &nnL[w]);
}

__device__ __forceinline__ void edge_cls_step(
    int i, int s, const float (*h2)[256], int tc, int b0, const float* cW,
    const float* cB, float* o_ef, float* o_el) {
  const int L = (i < 12) ? i : 12;
  const int tt = L - 1 - s;
  const int w = tc >> 6, lane = tc & 63, b = b0 + w;
  const int ridx = tt * 512 + b;
  const size_t orow = (size_t)(ebase(i) + tt) * 512 + b;
  uint32_t ea0, ea1, eb0, eb1;
  tf2x32(0u, 42u, 0u, (uint32_t)(i * 100 + 50), ea0, ea1);
  tf2x32(0u, 42u, 0u, (uint32_t)(i * 100 + 51), eb0, eb1);
  const float e0 = h2[w][lane];
  const float e1 = h2[w][lane + 64];
  const float e2 = h2[w][lane + 128];
  const float e3 = h2[w][lane + 192];
  edge_phase(e0, e1, e2, e3, lane, ridx, orow, cW + 51 * 256, cB + 51, 5, ea0,
             ea1, 0, 0, o_ef, o_el);
  edge_phase(e0, e1, e2, e3, lane, ridx, orow, cW + 56 * 256, cB + 56, 4, eb0,
             eb1, 5, 1, o_ef, o_el);
}

__device__ __forceinline__ void do_eih(const float4* __restrict__ Eih4,
                                       const float (*__restrict__ x)[256],
                                       int tc, float* __restrict__ egi,
                                       int slot, float eb0, float eb1,
                                       float eb2) {
  float a[3][NR];
  gemv3(Eih4, x, tc, a);
  float4* eg = (float4*)(egi + (size_t)slot * 3072 + tc * 12);
  eg[0] = {a[0][0] + eb0, a[1][0] + eb1, a[2][0] + eb2, a[0][1] + eb0};
  eg[1] = {a[1][1] + eb1, a[2][1] + eb2, a[0][2] + eb0, a[1][2] + eb1};
  eg[2] = {a[2][2] + eb2, a[0][3] + eb0, a[1][3] + eb1, a[2][3] + eb2};
}

// ---------------- the fused kernel ----------------
__global__ __launch_bounds__(NTHR, 2)
void fused_rnn(const float* __restrict__ nbih, const float* __restrict__ nbhh,
               const float* __restrict__ ebih, const float* __restrict__ ebhh,
               const float* __restrict__ ncW0, const float* __restrict__ ncb0,
               const float* __restrict__ ncW1, const float* __restrict__ ncb1,
               const float* __restrict__ ncW2, const float* __restrict__ ncb2,
               const float* __restrict__ ecW0, const float* __restrict__ ecb0,
               const float* __restrict__ ecW1, const float* __restrict__ ecb1,
               float* __restrict__ ws, float* __restrict__ out) {
  __shared__ float xb[2][NR][256];   // node_emb ping-pong
  __shared__ float ht[NR][256];      // node hidden input
  __shared__ float hs[2][NR][256];   // edge_h ping-pong
  __shared__ float clsW[60][256];    // classifier weights
  __shared__ float clsB[64];         // classifier biases
  __shared__ float nnL[NR];

  const int t = threadIdx.x;
  const int wg = blockIdx.x;
  const int b0 = wg * NR;
  const bool isg = t < 256;          // waves 0-3: GEMV; waves 4-7: classifiers
  const int tc = t & 255;

  const float4* W4q = (const float4*)(ws + WS_W4);
  const float4* Wih4 = W4q;
  const float4* Whh4 = W4q + MATS;
  const float4* Eih4 = W4q + 2 * MATS;
  const float4* Ehh4 = W4q + 3 * MATS;
  const float* h0 = ws + WS_H0;
  float* egi = ws + WS_EGI + (size_t)wg * 39936u;   // 13 slots * 3072

  float* o_nf = out + O_NF;
  float* o_ef = out + O_EF;
  float* o_nl = out + O_NL;
  float* o_el = out + O_EL;

  // ---- stage classifier weights/biases into LDS ----
  for (int x = t; x < 40 * 256; x += NTHR) (&clsW[0][0])[x] = ncW0[x];
  for (int x = t; x < 6 * 256; x += NTHR) (&clsW[40][0])[x] = ncW1[x];
  for (int x = t; x < 5 * 256; x += NTHR) (&clsW[46][0])[x] = ncW2[x];
  for (int x = t; x < 5 * 256; x += NTHR) (&clsW[51][0])[x] = ecW0[x];
  for (int x = t; x < 4 * 256; x += NTHR) (&clsW[56][0])[x] = ecW1[x];
  if (t < 40) clsB[t] = ncb0[t];
  else if (t < 46) clsB[t] = ncb1[t - 40];
  else if (t < 51) clsB[t] = ncb2[t - 46];
  else if (t < 56) clsB[t] = ecb0[t - 51];
  else if (t < 60) clsB[t] = ecb1[t - 56];

  const float nbih0 = nbih[tc], nbih1 = nbih[256 + tc], nbih2 = nbih[512 + tc];
  const float nbhh0 = nbhh[tc], nbhh1 = nbhh[256 + tc], nbhh2 = nbhh[512 + tc];
  const float ebih0 = ebih[tc], ebih1 = ebih[256 + tc], ebih2 = ebih[512 + tc];
  const float ebhh0 = ebhh[tc], ebhh1 = ebhh[256 + tc], ebhh2 = ebhh[512 + tc];

  if (isg) {
#pragma unroll
    for (int r = 0; r < NR; ++r) {
      hs[0][r][tc] = 0.f;
      ht[r][tc] = h0[(size_t)(b0 + r) * 256 + tc];
    }
  }
  if (t < NR) nnL[t] = -1.f;
  __syncthreads();

  int hp = 0;                        // hs[hp] holds current valid edge_h
  for (int i = 0; i < 50; ++i) {
    const int cur = i & 1, prv = cur ^ 1;
    const int L = (i < 12) ? i : 12;

    // ---- Phase A: build ht (gemv waves) ----
    if (i >= 1) {
      if (isg) {
#pragma unroll
        for (int r = 0; r < NR; ++r) {
          float v = xb[prv][r][tc];
          if (i >= 2) v += hs[hp][r][tc];
          ht[r][tc] = v;
        }
      }
      __syncthreads();
    }

    // ---- Phase B: node GRU (gemv) || deferred edge-cls(i-1, last) (cls) ----
    if (isg) {
      float gi[3][NR], gh[3][NR];
      if (i >= 1) {
        gemv6(Wih4, Whh4, xb[prv], ht, tc, gi, gh);
      } else {
        gemv3(Whh4, ht, tc, gh);
#pragma unroll
        for (int g = 0; g < 3; ++g)
#pragma unroll
          for (int r = 0; r < NR; ++r) gi[g][r] = 0.f;
      }
#pragma unroll
      for (int r = 0; r < NR; ++r) {
        float ir  = gi[0][r] + nbih0;
        float iz  = gi[1][r] + nbih1;
        float inn = gi[2][r] + nbih2;
        float hr = gh[0][r] + nbhh0;
        float hz = gh[1][r] + nbhh1;
        float hn = gh[2][r] + nbhh2;
        float h = ht[r][tc];
        float rr = 1.f / (1.f + expf(-(ir + hr)));
        float zg = 1.f / (1.f + expf(-(iz + hz)));
        float n = tanhf(inn + rr * hn);
        float hv = (1.f - zg) * n + zg * h;
        xb[cur][r][tc] = hv;
        if (i >= 1) hs[hp ^ 1][r][tc] = hs[hp][r][tc] + hv;  // edge_h += node_h
      }
    } else if (i >= 2) {
      const int Lp = ((i - 1) < 12) ? (i - 1) : 12;
      edge_cls_step(i - 1, Lp - 1, hs[hp], tc, b0, &clsW[0][0], clsB, o_ef,
                    o_el);
    }
    __syncthreads();
    if (i >= 1) hp ^= 1;

    // ---- Phase C: edge scan (gemv) || classifiers + eih (cls) ----
    if (i == 0) {
      if (isg) do_eih(Eih4, xb[cur], tc, egi, 0, ebih0, ebih1, ebih2);
      else node_cls_all(xb[cur], tc, b0, 0, &clsW[0][0], clsB, o_nf, o_nl,
                        nnL);
      __syncthreads();
    } else {
      const int sE = (L >= 2) ? 1 : 0;
      for (int s = 0; s < L; ++s) {
        if (isg) {
          const float* eg = egi + (size_t)((i - 1 - s) % 13) * 3072 + tc * 12;
          float4 f0 = *(const float4*)(eg);
          float4 f1 = *(const float4*)(eg + 4);
          float4 f2 = *(const float4*)(eg + 8);
          float a[3][NR];
          gemv3(Ehh4, hs[hp], tc, a);
          float ir_[NR] = {f0.x, f0.w, f1.z, f2.y};
          float iz_[NR] = {f0.y, f1.x, f1.w, f2.z};
          float in_[NR] = {f0.z, f1.y, f2.x, f2.w};
#pragma unroll
          for (int r = 0; r < NR; ++r) {
            float hr = a[0][r] + ebhh0;
            float hz = a[1][r] + ebhh1;
            float hn = a[2][r] + ebhh2;
            float h = hs[hp][r][tc];
            float rr = 1.f / (1.f + expf(-(ir_[r] + hr)));
            float zg = 1.f / (1.f + expf(-(iz_[r] + hz)));
            float n = tanhf(in_[r] + rr * hn);
            hs[hp ^ 1][r][tc] = (1.f - zg) * n + zg * h;
          }
        } else {
          if (s == 0)
            node_cls_all(xb[cur], tc, b0, i, &clsW[0][0], clsB, o_nf, o_nl,
                         nnL);
          if (s == sE && i <= 48)
            do_eih(Eih4, xb[cur], tc, egi, i % 13, ebih0, ebih1, ebih2);
          if (s >= 1)
            edge_cls_step(i, s - 1, hs[hp], tc, b0, &clsW[0][0], clsB, o_ef,
                          o_el);
        }
        __syncthreads();
        hp ^= 1;
      }
    }
  }

  // ---- final: last edge classifier + num_nodes ----
  if (!isg)
    edge_cls_step(49, 11, hs[hp], tc, b0, &clsW[0][0], clsB, o_ef, o_el);
  if (t < NR) {
    float v = nnL[t];
    __builtin_nontemporal_store((v == -1.f) ? 50.f : v, &out[b0 + t]);
  }
}

// ---------------- host ----------------
extern "C" void kernel_launch(void* const* d_in, const int* in_sizes, int n_in,
                              void* d_out, int out_size, void* d_ws,
                              size_t ws_size, hipStream_t stream) {
  (void)in_sizes; (void)n_in; (void)out_size; (void)ws_size;
  const float* z    = (const float*)d_in[0];
  const float* lpW  = (const float*)d_in[1];
  const float* lpb  = (const float*)d_in[2];
  const float* nWih = (const float*)d_in[3];
  const float* nWhh = (const float*)d_in[4];
  const float* nbih = (const float*)d_in[5];
  const float* nbhh = (const float*)d_in[6];
  const float* eWih = (const float*)d_in[7];
  const float* eWhh = (const float*)d_in[8];
  const float* ebih = (const float*)d_in[9];
  const float* ebhh = (const float*)d_in[10];
  const float* ncW0 = (const float*)d_in[11];
  const float* ncb0 = (const float*)d_in[12];
  const float* ncW1 = (const float*)d_in[13];
  const float* ncb1 = (const float*)d_in[14];
  const float* ncW2 = (const float*)d_in[15];
  const float* ncb2 = (const float*)d_in[16];
  const float* ecW0 = (const float*)d_in[17];
  const float* ecb0 = (const float*)d_in[18];
  const float* ecW1 = (const float*)d_in[19];
  const float* ecb1 = (const float*)d_in[20];

  setup_k<<<dim3(832), dim3(256), 0, stream>>>(nWih, nWhh, eWih, eWhh, z, lpW,
                                               lpb, (float*)d_ws);
  fused_rnn<<<dim3(NWG), dim3(NTHR), 0, stream>>>(
      nbih, nbhh, ebih, ebhh, ncW0, ncb0, ncW1, ncb1, ncW2, ncb2, ecW0, ecb0,
      ecW1, ecb1, (float*)d_ws, (float*)d_out);
}